// Round 2
// baseline (2574.781 us; speedup 1.0000x reference)
//
#include <hip/hip_runtime.h>
#include <hip/hip_bf16.h>

#define N_NODES 40000
#define N_EDGES 480000

__device__ __forceinline__ float bf2f(__hip_bfloat16 x) { return __bfloat162float(x); }

__device__ __forceinline__ float lane_bcast(float v, int i) {
    union { float f; int i; } u; u.f = v;
    int r = __builtin_amdgcn_readlane(u.i, i);
    union { int i; float f; } w; w.i = r; return w.f;
}

__device__ __forceinline__ float swishf(float x) { return x / (1.0f + __expf(-x)); }

__device__ __forceinline__ float bflo(unsigned u) { union { unsigned u; float f; } w; w.u = u << 16; return w.f; }
__device__ __forceinline__ float bfhi(unsigned u) { union { unsigned u; float f; } w; w.u = u & 0xffff0000u; return w.f; }

__constant__ const float INV8 = 0.35355339059327373f;
__constant__ const float INV64 = 0.125f;
__constant__ const float INV128 = 0.08838834764831845f;
__constant__ const float INV_NN = 0.2886751345948129f;   // 1/sqrt(12)
__constant__ const float SQRT2 = 1.4142135623730951f;
__constant__ const float SQRT3 = 1.7320508075688772f;
__constant__ const float INV_SQRT3 = 0.5773502691896258f;
__constant__ const float PI_F = 3.14159265358979323846f;

// dtype-generic load/store
template<bool F32>
__device__ __forceinline__ float LD(const void* p, int i) {
    if constexpr (F32) return ((const float*)p)[i];
    else return bf2f(((const __hip_bfloat16*)p)[i]);
}
template<bool F32>
__device__ __forceinline__ void ST(void* p, int i, float v) {
    if constexpr (F32) ((float*)p)[i] = v;
    else ((__hip_bfloat16*)p)[i] = __float2bfloat16(v);
}

// ---------------- dtype probe ----------------
// Reads even halfwords of W_up_s (4096 logical elements). If the buffer holds
// bf16, every even halfword is a genuine N(0,1) bf16 (exponent in a narrow
// band ~always). If it holds f32, even halfwords are low mantissa bits
// (exponent field ~uniform -> ~9% in band). flag=1 -> bf16, flag=0 -> f32.
__global__ void detect_kernel(const unsigned short* __restrict__ w, int* __restrict__ flag) {
    int lane = threadIdx.x;
    int cnt = 0;
    for (int i = lane; i < 2048; i += 64) {
        unsigned e = (w[2 * i] >> 7) & 0xFF;
        if (e >= 110 && e <= 133) cnt++;
    }
    #pragma unroll
    for (int off = 32; off > 0; off >>= 1) cnt += __shfl_down(cnt, off, 64);
    if (lane == 0) *flag = (cnt > 1024) ? 1 : 0;
}

// ---------------- Kernel A: per-node up-projection ----------------
// hbuf[n][0..63]=h_s, [64..127]=h_v.x, [128..191]=h_v.y, [192..255]=h_v.z (bf16)
template<bool F32>
__global__ __launch_bounds__(256) void node_up_kernel(
    const void* __restrict__ node_scalars,   // [N,64]
    const void* __restrict__ node_vectors,   // [N,64,3]
    const void* __restrict__ W_up_s,         // [64,64]
    const void* __restrict__ W_up_v,         // [64,64]
    __hip_bfloat16* __restrict__ hbuf,       // [N,256]
    const int* __restrict__ flag)
{
    if ((*flag != 0) == F32) return;   // uniform; before any __syncthreads
    __shared__ float WsL[4096];
    __shared__ float WvL[4096];
    int tid = threadIdx.x;
    for (int idx = tid; idx < 4096; idx += 256) {
        WsL[idx] = LD<F32>(W_up_s, idx);
        WvL[idx] = LD<F32>(W_up_v, idx);
    }
    __syncthreads();
    int wave = tid >> 6, lane = tid & 63;
    for (int n = blockIdx.x * 4 + wave; n < N_NODES; n += gridDim.x * 4) {
        float s_in = LD<F32>(node_scalars, n * 64 + lane);
        float v0 = LD<F32>(node_vectors, n * 192 + lane * 3 + 0);
        float v1 = LD<F32>(node_vectors, n * 192 + lane * 3 + 1);
        float v2 = LD<F32>(node_vectors, n * 192 + lane * 3 + 2);
        float hs = 0.f, hv0 = 0.f, hv1 = 0.f, hv2 = 0.f;
        for (int i = 0; i < 64; i++) {
            float si = lane_bcast(s_in, i);
            hs = fmaf(si, WsL[i * 64 + lane], hs);
            float w = WvL[i * 64 + lane];
            hv0 = fmaf(lane_bcast(v0, i), w, hv0);
            hv1 = fmaf(lane_bcast(v1, i), w, hv1);
            hv2 = fmaf(lane_bcast(v2, i), w, hv2);
        }
        __hip_bfloat16* hp = hbuf + (size_t)n * 256;
        hp[lane]       = __float2bfloat16(hs * INV64);
        hp[64 + lane]  = __float2bfloat16(hv0 * INV64);
        hp[128 + lane] = __float2bfloat16(hv1 * INV64);
        hp[192 + lane] = __float2bfloat16(hv2 * INV64);
    }
}

// ---------------- Kernel B: per-edge message + scatter ----------------
template<bool F32>
__global__ __launch_bounds__(256) void edge_kernel(
    const void* __restrict__ vectors,   // [E,3]
    const int* __restrict__ senders,
    const int* __restrict__ receivers,
    const void* __restrict__ W1,        // [8,64]
    const void* __restrict__ W2,        // [64,64]
    const void* __restrict__ W3,        // [64,256]
    const __hip_bfloat16* __restrict__ hbuf,  // [N,256]
    float* __restrict__ agg_s,          // [N,128]
    float* __restrict__ agg_v,          // [N,384] layout [c][128]
    const int* __restrict__ flag)
{
    if ((*flag != 0) == F32) return;
    __shared__ float W1L[512];
    __shared__ float W2L[4096];
    int tid = threadIdx.x;
    for (int idx = tid; idx < 512; idx += 256) W1L[idx] = LD<F32>(W1, idx);
    for (int idx = tid; idx < 4096; idx += 256) W2L[idx] = LD<F32>(W2, idx);
    __syncthreads();
    int wave = tid >> 6, lane = tid & 63;
    for (int e = blockIdx.x * 4 + wave; e < N_EDGES; e += gridDim.x * 4) {
        float vx = LD<F32>(vectors, e * 3 + 0);
        float vy = LD<F32>(vectors, e * 3 + 1);
        float vz = LD<F32>(vectors, e * 3 + 2);
        float len2 = vx * vx + vy * vy + vz * vz;
        float len = sqrtf(len2);
        float Yx = 0.f, Yy = 0.f, Yz = 0.f;
        float rb[8];
        if (len > 0.f) {
            float inv = 1.f / len;
            Yx = SQRT3 * vx * inv; Yy = SQRT3 * vy * inv; Yz = SQRT3 * vz * inv;
            float x6 = len2 * len2 * len2;
            float env = (len < 1.f) ? fmaf(x6, fmaf(len, fmaf(len, -21.f, 48.f), -28.f), 1.f) : 0.f;
            float c = SQRT2 * inv * env;
            #pragma unroll
            for (int k = 0; k < 8; k++) rb[k] = c * __sinf((float)(k + 1) * PI_F * len);
        } else {
            #pragma unroll
            for (int k = 0; k < 8; k++) rb[k] = 0.f;
        }
        float a = 0.f;
        #pragma unroll
        for (int k = 0; k < 8; k++) a = fmaf(rb[k], W1L[k * 64 + lane], a);
        float h1 = swishf(a * INV8);
        a = 0.f;
        for (int i = 0; i < 64; i++)
            a = fmaf(lane_bcast(h1, i), W2L[i * 64 + lane], a);
        float h2 = swishf(a * INV64);
        // layer 3: lane computes cols 4*lane..4*lane+3, coalesced vector loads
        float m0 = 0.f, m1 = 0.f, m2 = 0.f, m3 = 0.f;
        for (int i = 0; i < 64; i++) {
            float h2i = lane_bcast(h2, i);
            if constexpr (F32) {
                float4 w = *(const float4*)((const float*)W3 + i * 256 + 4 * lane);
                m0 = fmaf(h2i, w.x, m0);
                m1 = fmaf(h2i, w.y, m1);
                m2 = fmaf(h2i, w.z, m2);
                m3 = fmaf(h2i, w.w, m3);
            } else {
                uint2 w = *(const uint2*)((const __hip_bfloat16*)W3 + i * 256 + 4 * lane);
                m0 = fmaf(h2i, bflo(w.x), m0);
                m1 = fmaf(h2i, bfhi(w.x), m1);
                m2 = fmaf(h2i, bflo(w.y), m2);
                m3 = fmaf(h2i, bfhi(w.y), m3);
            }
        }
        m0 *= INV64; m1 *= INV64; m2 *= INV64; m3 *= INV64;
        // redistribute: lane needs mix[lane], mix[64+lane], mix[128+lane], mix[192+lane]
        int base = lane >> 2, r = lane & 3;
        float mix_s0, mix_s1, mix_v0, mix_v1;
        {
            int s0 = base, s1 = 16 + base, s2 = 32 + base, s3 = 48 + base;
            float a0, a1, a2, a3, lo, hi;
            a0 = __shfl(m0, s0); a1 = __shfl(m1, s0); a2 = __shfl(m2, s0); a3 = __shfl(m3, s0);
            lo = (r & 1) ? a1 : a0; hi = (r & 1) ? a3 : a2; mix_s0 = (r & 2) ? hi : lo;
            a0 = __shfl(m0, s1); a1 = __shfl(m1, s1); a2 = __shfl(m2, s1); a3 = __shfl(m3, s1);
            lo = (r & 1) ? a1 : a0; hi = (r & 1) ? a3 : a2; mix_s1 = (r & 2) ? hi : lo;
            a0 = __shfl(m0, s2); a1 = __shfl(m1, s2); a2 = __shfl(m2, s2); a3 = __shfl(m3, s2);
            lo = (r & 1) ? a1 : a0; hi = (r & 1) ? a3 : a2; mix_v0 = (r & 2) ? hi : lo;
            a0 = __shfl(m0, s3); a1 = __shfl(m1, s3); a2 = __shfl(m2, s3); a3 = __shfl(m3, s3);
            lo = (r & 1) ? a1 : a0; hi = (r & 1) ? a3 : a2; mix_v1 = (r & 2) ? hi : lo;
        }
        int snd = senders[e], rcv = receivers[e];
        const __hip_bfloat16* hp = hbuf + (size_t)snd * 256;
        float m_s = bf2f(hp[lane]);
        float mv0 = bf2f(hp[64 + lane]);
        float mv1 = bf2f(hp[128 + lane]);
        float mv2 = bf2f(hp[192 + lane]);
        float tp0 = (mv0 * Yx + mv1 * Yy + mv2 * Yz) * INV_SQRT3;
        float t1x = m_s * Yx, t1y = m_s * Yy, t1z = m_s * Yz;
        float* aS = agg_s + (size_t)rcv * 128;
        unsafeAtomicAdd(aS + lane,      m_s * mix_s0);
        unsafeAtomicAdd(aS + 64 + lane, tp0 * mix_s1);
        float* aV = agg_v + (size_t)rcv * 384;
        unsafeAtomicAdd(aV + lane,        mv0 * mix_v0);
        unsafeAtomicAdd(aV + 64 + lane,   t1x * mix_v1);
        unsafeAtomicAdd(aV + 128 + lane,  mv1 * mix_v0);
        unsafeAtomicAdd(aV + 192 + lane,  t1y * mix_v1);
        unsafeAtomicAdd(aV + 256 + lane,  mv2 * mix_v0);
        unsafeAtomicAdd(aV + 320 + lane,  t1z * mix_v1);
    }
}

// ---------------- Kernel C: per-node down-projection + skip + gate ----------------
template<bool F32>
__global__ __launch_bounds__(256) void node_final_kernel(
    const void* __restrict__ node_scalars,   // [N,64]
    const void* __restrict__ node_vectors,   // [N,64,3]
    const int* __restrict__ node_specie,     // [N]
    const void* __restrict__ W_skip_s,       // [5,64,128]
    const void* __restrict__ W_skip_v,       // [5,64,64]
    const void* __restrict__ W_down_s,       // [128,128]
    const void* __restrict__ W_down_v,       // [128,64]
    const float* __restrict__ agg_s,         // [N,128]
    const float* __restrict__ agg_v,         // [N,384]
    void* __restrict__ out,                  // [N,256]
    const int* __restrict__ flag)
{
    if ((*flag != 0) == F32) return;
    __shared__ float WdsL[16384];
    __shared__ float WdvL[8192];
    int tid = threadIdx.x;
    for (int idx = tid; idx < 16384; idx += 256) WdsL[idx] = LD<F32>(W_down_s, idx);
    for (int idx = tid; idx < 8192; idx += 256) WdvL[idx] = LD<F32>(W_down_v, idx);
    __syncthreads();
    int wave = tid >> 6, lane = tid & 63;
    const float SC = INV128 * INV_NN;
    for (int n = blockIdx.x * 4 + wave; n < N_NODES; n += gridDim.x * 4) {
        int sp = node_specie[n];
        const float* ags = agg_s + (size_t)n * 128;
        const float* agv = agg_v + (size_t)n * 384;
        float as0 = ags[lane], as1 = ags[64 + lane];
        float av00 = agv[lane],       av01 = agv[64 + lane];
        float av10 = agv[128 + lane], av11 = agv[192 + lane];
        float av20 = agv[256 + lane], av21 = agv[320 + lane];
        float s_in = LD<F32>(node_scalars, n * 64 + lane);
        float vi0 = LD<F32>(node_vectors, n * 192 + lane * 3 + 0);
        float vi1 = LD<F32>(node_vectors, n * 192 + lane * 3 + 1);
        float vi2 = LD<F32>(node_vectors, n * 192 + lane * 3 + 2);
        int wss_off = sp * 8192, wsv_off = sp * 4096;
        float ds0 = 0.f, ds1 = 0.f, dv0 = 0.f, dv1 = 0.f, dv2 = 0.f;
        float scs0 = 0.f, scs1 = 0.f, scv0 = 0.f, scv1 = 0.f, scv2 = 0.f;
        for (int i = 0; i < 64; i++) {
            float a0 = lane_bcast(as0, i), a1 = lane_bcast(as1, i);
            ds0 = fmaf(a0, WdsL[i * 128 + lane], ds0);
            ds0 = fmaf(a1, WdsL[(64 + i) * 128 + lane], ds0);
            ds1 = fmaf(a0, WdsL[i * 128 + 64 + lane], ds1);
            ds1 = fmaf(a1, WdsL[(64 + i) * 128 + 64 + lane], ds1);
            float w0 = WdvL[i * 64 + lane], w1 = WdvL[(64 + i) * 64 + lane];
            dv0 = fmaf(lane_bcast(av00, i), w0, dv0); dv0 = fmaf(lane_bcast(av01, i), w1, dv0);
            dv1 = fmaf(lane_bcast(av10, i), w0, dv1); dv1 = fmaf(lane_bcast(av11, i), w1, dv1);
            dv2 = fmaf(lane_bcast(av20, i), w0, dv2); dv2 = fmaf(lane_bcast(av21, i), w1, dv2);
            float si = lane_bcast(s_in, i);
            scs0 = fmaf(si, LD<F32>(W_skip_s, wss_off + i * 128 + lane), scs0);
            scs1 = fmaf(si, LD<F32>(W_skip_s, wss_off + i * 128 + 64 + lane), scs1);
            float wv = LD<F32>(W_skip_v, wsv_off + i * 64 + lane);
            scv0 = fmaf(lane_bcast(vi0, i), wv, scv0);
            scv1 = fmaf(lane_bcast(vi1, i), wv, scv1);
            scv2 = fmaf(lane_bcast(vi2, i), wv, scv2);
        }
        float d_s0 = ds0 * SC + scs0 * INV64;
        float d_s1 = ds1 * SC + scs1 * INV64;
        float outs = swishf(d_s0);
        float g = swishf(d_s1);
        float o0 = (dv0 * SC + scv0 * INV64) * g;
        float o1 = (dv1 * SC + scv1 * INV64) * g;
        float o2 = (dv2 * SC + scv2 * INV64) * g;
        int ob = n * 256;
        ST<F32>(out, ob + lane, outs);
        ST<F32>(out, ob + 64 + lane * 3 + 0, o0);
        ST<F32>(out, ob + 64 + lane * 3 + 1, o1);
        ST<F32>(out, ob + 64 + lane * 3 + 2, o2);
    }
}

extern "C" void kernel_launch(void* const* d_in, const int* in_sizes, int n_in,
                              void* d_out, int out_size, void* d_ws, size_t ws_size,
                              hipStream_t stream) {
    const void* vectors      = d_in[0];
    const void* node_scalars = d_in[1];
    const void* node_vectors = d_in[2];
    const int* node_specie   = (const int*)d_in[3];
    const int* senders       = (const int*)d_in[4];
    const int* receivers     = (const int*)d_in[5];
    const void* W_up_s       = d_in[6];
    const void* W_up_v       = d_in[7];
    const void* W_skip_s     = d_in[8];
    const void* W_skip_v     = d_in[9];
    const void* W_mlp1       = d_in[10];
    const void* W_mlp2       = d_in[11];
    const void* W_mlp3       = d_in[12];
    const void* W_down_s     = d_in[13];
    const void* W_down_v     = d_in[14];

    char* ws = (char*)d_ws;
    __hip_bfloat16* hbuf = (__hip_bfloat16*)ws;                     // 20.48 MB
    float* agg_s = (float*)(ws + (size_t)N_NODES * 256 * 2);        // 20.48 MB
    float* agg_v = (float*)(ws + (size_t)N_NODES * 256 * 2
                               + (size_t)N_NODES * 128 * 4);        // 61.44 MB
    int* flag = (int*)(ws + (size_t)N_NODES * 256 * 2
                          + (size_t)N_NODES * (128 + 384) * 4);     // +4 B

    detect_kernel<<<dim3(1), dim3(64), 0, stream>>>((const unsigned short*)W_up_s, flag);
    hipMemsetAsync(agg_s, 0, (size_t)N_NODES * (128 + 384) * 4, stream);

    node_up_kernel<true><<<dim3(2500), dim3(256), 0, stream>>>(
        node_scalars, node_vectors, W_up_s, W_up_v, hbuf, flag);
    node_up_kernel<false><<<dim3(2500), dim3(256), 0, stream>>>(
        node_scalars, node_vectors, W_up_s, W_up_v, hbuf, flag);

    edge_kernel<true><<<dim3(2500), dim3(256), 0, stream>>>(
        vectors, senders, receivers, W_mlp1, W_mlp2, W_mlp3, hbuf, agg_s, agg_v, flag);
    edge_kernel<false><<<dim3(2500), dim3(256), 0, stream>>>(
        vectors, senders, receivers, W_mlp1, W_mlp2, W_mlp3, hbuf, agg_s, agg_v, flag);

    node_final_kernel<true><<<dim3(2500), dim3(256), 0, stream>>>(
        node_scalars, node_vectors, node_specie, W_skip_s, W_skip_v,
        W_down_s, W_down_v, agg_s, agg_v, d_out, flag);
    node_final_kernel<false><<<dim3(2500), dim3(256), 0, stream>>>(
        node_scalars, node_vectors, node_specie, W_skip_s, W_skip_v,
        W_down_s, W_down_v, agg_s, agg_v, d_out, flag);
}

// Round 3
// 1771.761 us; speedup vs baseline: 1.4532x; 1.4532x over previous
//
#include <hip/hip_runtime.h>
#include <hip/hip_bf16.h>

#define N_NODES 40000
#define N_EDGES 480000

__device__ __forceinline__ float bf2f(__hip_bfloat16 x) { return __bfloat162float(x); }

__device__ __forceinline__ float lane_bcast(float v, int i) {
    union { float f; int i; } u; u.f = v;
    int r = __builtin_amdgcn_readlane(u.i, i);
    union { int i; float f; } w; w.i = r; return w.f;
}

__device__ __forceinline__ float swishf(float x) { return x / (1.0f + __expf(-x)); }

__device__ __forceinline__ float bflo(unsigned u) { union { unsigned u; float f; } w; w.u = u << 16; return w.f; }
__device__ __forceinline__ float bfhi(unsigned u) { union { unsigned u; float f; } w; w.u = u & 0xffff0000u; return w.f; }

__device__ __forceinline__ unsigned short f2bf_bits(float x) {
    union { __hip_bfloat16 h; unsigned short u; } c; c.h = __float2bfloat16(x); return c.u;
}

__constant__ const float INV8 = 0.35355339059327373f;
__constant__ const float INV64 = 0.125f;
__constant__ const float INV128 = 0.08838834764831845f;
__constant__ const float INV_NN = 0.2886751345948129f;   // 1/sqrt(12)
__constant__ const float SQRT2 = 1.4142135623730951f;
__constant__ const float SQRT3 = 1.7320508075688772f;
__constant__ const float INV_SQRT3 = 0.5773502691896258f;
__constant__ const float PI_F = 3.14159265358979323846f;

template<bool F32>
__device__ __forceinline__ float LD(const void* p, int i) {
    if constexpr (F32) return ((const float*)p)[i];
    else return bf2f(((const __hip_bfloat16*)p)[i]);
}
template<bool F32>
__device__ __forceinline__ void ST(void* p, int i, float v) {
    if constexpr (F32) ((float*)p)[i] = v;
    else ((__hip_bfloat16*)p)[i] = __float2bfloat16(v);
}

// ---------------- dtype probe ----------------
__global__ void detect_kernel(const unsigned short* __restrict__ w, int* __restrict__ flag) {
    int lane = threadIdx.x;
    int cnt = 0;
    for (int i = lane; i < 2048; i += 64) {
        unsigned e = (w[2 * i] >> 7) & 0xFF;
        if (e >= 110 && e <= 133) cnt++;
    }
    #pragma unroll
    for (int off = 32; off > 0; off >>= 1) cnt += __shfl_down(cnt, off, 64);
    if (lane == 0) *flag = (cnt > 1024) ? 1 : 0;
}

// ---------------- counting sort by receiver ----------------
__global__ __launch_bounds__(256) void hist_kernel(const int* __restrict__ receivers,
                                                   int* __restrict__ cnt) {
    int e = blockIdx.x * 256 + threadIdx.x;
    if (e < N_EDGES) atomicAdd(&cnt[receivers[e]], 1);
}

__global__ __launch_bounds__(1024) void scan_kernel(const int* __restrict__ cnt,
                                                    int* __restrict__ offs,
                                                    int* __restrict__ cursor) {
    __shared__ int part[1024];
    int t = threadIdx.x;
    const int CH = 40;                       // 1024*40 >= 40000
    int base = t * CH;
    int s = 0;
    #pragma unroll 4
    for (int i = 0; i < CH; i++) {
        int idx = base + i;
        if (idx < N_NODES) s += cnt[idx];
    }
    part[t] = s;
    __syncthreads();
    for (int off = 1; off < 1024; off <<= 1) {
        int tmp = (t >= off) ? part[t - off] : 0;
        __syncthreads();
        part[t] += tmp;
        __syncthreads();
    }
    int run = part[t] - s;                   // exclusive prefix of this chunk
    for (int i = 0; i < CH; i++) {
        int idx = base + i;
        if (idx < N_NODES) {
            offs[idx] = run;
            cursor[idx] = run;
            run += cnt[idx];
        }
    }
    if (t == 1023) offs[N_NODES] = part[1023];
}

__global__ __launch_bounds__(256) void scatter_kernel(const int* __restrict__ receivers,
                                                      int* __restrict__ cursor,
                                                      int* __restrict__ sorted_eid) {
    int e = blockIdx.x * 256 + threadIdx.x;
    if (e < N_EDGES) {
        int p = atomicAdd(&cursor[receivers[e]], 1);
        sorted_eid[p] = e;
    }
}

// ---------------- Kernel A: per-node up-projection ----------------
// hbuf[n][0..63]=h_s, [64..127]=h_v.x, [128..191]=h_v.y, [192..255]=h_v.z (bf16)
template<bool F32>
__global__ __launch_bounds__(256) void node_up_kernel(
    const void* __restrict__ node_scalars,   // [N,64]
    const void* __restrict__ node_vectors,   // [N,64,3]
    const void* __restrict__ W_up_s,         // [64,64]
    const void* __restrict__ W_up_v,         // [64,64]
    __hip_bfloat16* __restrict__ hbuf,       // [N,256]
    const int* __restrict__ flag)
{
    if ((*flag != 0) == F32) return;
    __shared__ float WsL[4096];
    __shared__ float WvL[4096];
    int tid = threadIdx.x;
    for (int idx = tid; idx < 4096; idx += 256) {
        WsL[idx] = LD<F32>(W_up_s, idx);
        WvL[idx] = LD<F32>(W_up_v, idx);
    }
    __syncthreads();
    int wave = tid >> 6, lane = tid & 63;
    for (int n = blockIdx.x * 4 + wave; n < N_NODES; n += gridDim.x * 4) {
        float s_in = LD<F32>(node_scalars, n * 64 + lane);
        float v0 = LD<F32>(node_vectors, n * 192 + lane * 3 + 0);
        float v1 = LD<F32>(node_vectors, n * 192 + lane * 3 + 1);
        float v2 = LD<F32>(node_vectors, n * 192 + lane * 3 + 2);
        float hs = 0.f, hv0 = 0.f, hv1 = 0.f, hv2 = 0.f;
        for (int i = 0; i < 64; i++) {
            float si = lane_bcast(s_in, i);
            hs = fmaf(si, WsL[i * 64 + lane], hs);
            float w = WvL[i * 64 + lane];
            hv0 = fmaf(lane_bcast(v0, i), w, hv0);
            hv1 = fmaf(lane_bcast(v1, i), w, hv1);
            hv2 = fmaf(lane_bcast(v2, i), w, hv2);
        }
        __hip_bfloat16* hp = hbuf + (size_t)n * 256;
        hp[lane]       = __float2bfloat16(hs * INV64);
        hp[64 + lane]  = __float2bfloat16(hv0 * INV64);
        hp[128 + lane] = __float2bfloat16(hv1 * INV64);
        hp[192 + lane] = __float2bfloat16(hv2 * INV64);
    }
}

// ---------------- Kernel B: owner-compute edge aggregation (no atomics) ----------------
// One wave per receiver node; walks its sorted edge run, accumulates in registers.
template<bool F32>
__global__ __launch_bounds__(256) void agg_kernel(
    const void* __restrict__ vectors,        // [E,3]
    const int* __restrict__ senders,
    const int* __restrict__ sorted_eid,      // [E]
    const int* __restrict__ offs,            // [N+1]
    const void* __restrict__ W1,             // [8,64]
    const void* __restrict__ W2,             // [64,64]
    const void* __restrict__ W3,             // [64,256]
    const __hip_bfloat16* __restrict__ hbuf, // [N,256]
    float* __restrict__ agg_s,               // [N,128]
    float* __restrict__ agg_v,               // [N,384]
    const int* __restrict__ flag)
{
    if ((*flag != 0) == F32) return;
    __shared__ float W1L[512];
    __shared__ float W2L[4096];
    __shared__ unsigned W3L[8192];           // bf16 pairs: row i, cols 2j,2j+1
    int tid = threadIdx.x;
    for (int idx = tid; idx < 512; idx += 256) W1L[idx] = LD<F32>(W1, idx);
    for (int idx = tid; idx < 4096; idx += 256) W2L[idx] = LD<F32>(W2, idx);
    if constexpr (F32) {
        const float* w3 = (const float*)W3;
        for (int k = tid; k < 8192; k += 256) {
            unsigned lo = f2bf_bits(w3[2 * k]);
            unsigned hi = f2bf_bits(w3[2 * k + 1]);
            W3L[k] = lo | (hi << 16);
        }
    } else {
        const unsigned* w3 = (const unsigned*)W3;
        for (int k = tid; k < 8192; k += 256) W3L[k] = w3[k];
    }
    __syncthreads();
    int wave = tid >> 6, lane = tid & 63;
    for (int n = blockIdx.x * 4 + wave; n < N_NODES; n += gridDim.x * 4) {
        int beg = offs[n], end = offs[n + 1];
        float acc_s0 = 0.f, acc_s1 = 0.f;
        float av0 = 0.f, av1 = 0.f, av2 = 0.f, av3 = 0.f, av4 = 0.f, av5 = 0.f;
        for (int p = beg; p < end; p++) {
            int e = sorted_eid[p];
            int snd = senders[e];
            const __hip_bfloat16* hp = hbuf + (size_t)snd * 256;
            float m_s = bf2f(hp[lane]);
            float mv0 = bf2f(hp[64 + lane]);
            float mv1 = bf2f(hp[128 + lane]);
            float mv2 = bf2f(hp[192 + lane]);
            float vx = LD<F32>(vectors, e * 3 + 0);
            float vy = LD<F32>(vectors, e * 3 + 1);
            float vz = LD<F32>(vectors, e * 3 + 2);
            float len2 = vx * vx + vy * vy + vz * vz;
            float len = sqrtf(len2);
            float Yx = 0.f, Yy = 0.f, Yz = 0.f;
            float rb[8];
            if (len > 0.f) {
                float inv = 1.f / len;
                Yx = SQRT3 * vx * inv; Yy = SQRT3 * vy * inv; Yz = SQRT3 * vz * inv;
                float x6 = len2 * len2 * len2;
                float env = (len < 1.f) ? fmaf(x6, fmaf(len, fmaf(len, -21.f, 48.f), -28.f), 1.f) : 0.f;
                float c = SQRT2 * inv * env;
                #pragma unroll
                for (int k = 0; k < 8; k++) rb[k] = c * __sinf((float)(k + 1) * PI_F * len);
            } else {
                #pragma unroll
                for (int k = 0; k < 8; k++) rb[k] = 0.f;
            }
            float a = 0.f;
            #pragma unroll
            for (int k = 0; k < 8; k++) a = fmaf(rb[k], W1L[k * 64 + lane], a);
            float h1 = swishf(a * INV8);
            a = 0.f;
            for (int i = 0; i < 64; i++)
                a = fmaf(lane_bcast(h1, i), W2L[i * 64 + lane], a);
            float h2 = swishf(a * INV64);
            // layer 3: lane computes cols 4*lane..4*lane+3 from LDS bf16
            float m0 = 0.f, m1 = 0.f, m2 = 0.f, m3 = 0.f;
            for (int i = 0; i < 64; i++) {
                float h2i = lane_bcast(h2, i);
                uint2 w = *(const uint2*)(W3L + i * 128 + 2 * lane);
                m0 = fmaf(h2i, bflo(w.x), m0);
                m1 = fmaf(h2i, bfhi(w.x), m1);
                m2 = fmaf(h2i, bflo(w.y), m2);
                m3 = fmaf(h2i, bfhi(w.y), m3);
            }
            m0 *= INV64; m1 *= INV64; m2 *= INV64; m3 *= INV64;
            // redistribute: lane needs mix[lane], mix[64+lane], mix[128+lane], mix[192+lane]
            int base = lane >> 2, r = lane & 3;
            float mix_s0, mix_s1, mix_v0, mix_v1;
            {
                int s0 = base, s1 = 16 + base, s2 = 32 + base, s3 = 48 + base;
                float a0, a1, a2, a3, lo, hi;
                a0 = __shfl(m0, s0); a1 = __shfl(m1, s0); a2 = __shfl(m2, s0); a3 = __shfl(m3, s0);
                lo = (r & 1) ? a1 : a0; hi = (r & 1) ? a3 : a2; mix_s0 = (r & 2) ? hi : lo;
                a0 = __shfl(m0, s1); a1 = __shfl(m1, s1); a2 = __shfl(m2, s1); a3 = __shfl(m3, s1);
                lo = (r & 1) ? a1 : a0; hi = (r & 1) ? a3 : a2; mix_s1 = (r & 2) ? hi : lo;
                a0 = __shfl(m0, s2); a1 = __shfl(m1, s2); a2 = __shfl(m2, s2); a3 = __shfl(m3, s2);
                lo = (r & 1) ? a1 : a0; hi = (r & 1) ? a3 : a2; mix_v0 = (r & 2) ? hi : lo;
                a0 = __shfl(m0, s3); a1 = __shfl(m1, s3); a2 = __shfl(m2, s3); a3 = __shfl(m3, s3);
                lo = (r & 1) ? a1 : a0; hi = (r & 1) ? a3 : a2; mix_v1 = (r & 2) ? hi : lo;
            }
            float tp0 = (mv0 * Yx + mv1 * Yy + mv2 * Yz) * INV_SQRT3;
            acc_s0 = fmaf(m_s, mix_s0, acc_s0);
            acc_s1 = fmaf(tp0, mix_s1, acc_s1);
            float t1 = m_s * mix_v1;
            av0 = fmaf(mv0, mix_v0, av0);
            av1 = fmaf(t1, Yx, av1);
            av2 = fmaf(mv1, mix_v0, av2);
            av3 = fmaf(t1, Yy, av3);
            av4 = fmaf(mv2, mix_v0, av4);
            av5 = fmaf(t1, Yz, av5);
        }
        float* aS = agg_s + (size_t)n * 128;
        aS[lane] = acc_s0;
        aS[64 + lane] = acc_s1;
        float* aV = agg_v + (size_t)n * 384;
        aV[lane] = av0;
        aV[64 + lane] = av1;
        aV[128 + lane] = av2;
        aV[192 + lane] = av3;
        aV[256 + lane] = av4;
        aV[320 + lane] = av5;
    }
}

// ---------------- Kernel C: per-node down-projection + skip + gate ----------------
template<bool F32>
__global__ __launch_bounds__(256) void node_final_kernel(
    const void* __restrict__ node_scalars,   // [N,64]
    const void* __restrict__ node_vectors,   // [N,64,3]
    const int* __restrict__ node_specie,     // [N]
    const void* __restrict__ W_skip_s,       // [5,64,128]
    const void* __restrict__ W_skip_v,       // [5,64,64]
    const void* __restrict__ W_down_s,       // [128,128]
    const void* __restrict__ W_down_v,       // [128,64]
    const float* __restrict__ agg_s,         // [N,128]
    const float* __restrict__ agg_v,         // [N,384]
    void* __restrict__ out,                  // [N,256]
    const int* __restrict__ flag)
{
    if ((*flag != 0) == F32) return;
    __shared__ float WdsL[16384];
    __shared__ float WdvL[8192];
    int tid = threadIdx.x;
    for (int idx = tid; idx < 16384; idx += 256) WdsL[idx] = LD<F32>(W_down_s, idx);
    for (int idx = tid; idx < 8192; idx += 256) WdvL[idx] = LD<F32>(W_down_v, idx);
    __syncthreads();
    int wave = tid >> 6, lane = tid & 63;
    const float SC = INV128 * INV_NN;
    for (int n = blockIdx.x * 4 + wave; n < N_NODES; n += gridDim.x * 4) {
        int sp = node_specie[n];
        const float* ags = agg_s + (size_t)n * 128;
        const float* agv = agg_v + (size_t)n * 384;
        float as0 = ags[lane], as1 = ags[64 + lane];
        float av00 = agv[lane],       av01 = agv[64 + lane];
        float av10 = agv[128 + lane], av11 = agv[192 + lane];
        float av20 = agv[256 + lane], av21 = agv[320 + lane];
        float s_in = LD<F32>(node_scalars, n * 64 + lane);
        float vi0 = LD<F32>(node_vectors, n * 192 + lane * 3 + 0);
        float vi1 = LD<F32>(node_vectors, n * 192 + lane * 3 + 1);
        float vi2 = LD<F32>(node_vectors, n * 192 + lane * 3 + 2);
        int wss_off = sp * 8192, wsv_off = sp * 4096;
        float ds0 = 0.f, ds1 = 0.f, dv0 = 0.f, dv1 = 0.f, dv2 = 0.f;
        float scs0 = 0.f, scs1 = 0.f, scv0 = 0.f, scv1 = 0.f, scv2 = 0.f;
        for (int i = 0; i < 64; i++) {
            float a0 = lane_bcast(as0, i), a1 = lane_bcast(as1, i);
            ds0 = fmaf(a0, WdsL[i * 128 + lane], ds0);
            ds0 = fmaf(a1, WdsL[(64 + i) * 128 + lane], ds0);
            ds1 = fmaf(a0, WdsL[i * 128 + 64 + lane], ds1);
            ds1 = fmaf(a1, WdsL[(64 + i) * 128 + 64 + lane], ds1);
            float w0 = WdvL[i * 64 + lane], w1 = WdvL[(64 + i) * 64 + lane];
            dv0 = fmaf(lane_bcast(av00, i), w0, dv0); dv0 = fmaf(lane_bcast(av01, i), w1, dv0);
            dv1 = fmaf(lane_bcast(av10, i), w0, dv1); dv1 = fmaf(lane_bcast(av11, i), w1, dv1);
            dv2 = fmaf(lane_bcast(av20, i), w0, dv2); dv2 = fmaf(lane_bcast(av21, i), w1, dv2);
            float si = lane_bcast(s_in, i);
            scs0 = fmaf(si, LD<F32>(W_skip_s, wss_off + i * 128 + lane), scs0);
            scs1 = fmaf(si, LD<F32>(W_skip_s, wss_off + i * 128 + 64 + lane), scs1);
            float wv = LD<F32>(W_skip_v, wsv_off + i * 64 + lane);
            scv0 = fmaf(lane_bcast(vi0, i), wv, scv0);
            scv1 = fmaf(lane_bcast(vi1, i), wv, scv1);
            scv2 = fmaf(lane_bcast(vi2, i), wv, scv2);
        }
        float d_s0 = ds0 * SC + scs0 * INV64;
        float d_s1 = ds1 * SC + scs1 * INV64;
        float outs = swishf(d_s0);
        float g = swishf(d_s1);
        float o0 = (dv0 * SC + scv0 * INV64) * g;
        float o1 = (dv1 * SC + scv1 * INV64) * g;
        float o2 = (dv2 * SC + scv2 * INV64) * g;
        int ob = n * 256;
        ST<F32>(out, ob + lane, outs);
        ST<F32>(out, ob + 64 + lane * 3 + 0, o0);
        ST<F32>(out, ob + 64 + lane * 3 + 1, o1);
        ST<F32>(out, ob + 64 + lane * 3 + 2, o2);
    }
}

extern "C" void kernel_launch(void* const* d_in, const int* in_sizes, int n_in,
                              void* d_out, int out_size, void* d_ws, size_t ws_size,
                              hipStream_t stream) {
    const void* vectors      = d_in[0];
    const void* node_scalars = d_in[1];
    const void* node_vectors = d_in[2];
    const int* node_specie   = (const int*)d_in[3];
    const int* senders       = (const int*)d_in[4];
    const int* receivers     = (const int*)d_in[5];
    const void* W_up_s       = d_in[6];
    const void* W_up_v       = d_in[7];
    const void* W_skip_s     = d_in[8];
    const void* W_skip_v     = d_in[9];
    const void* W_mlp1       = d_in[10];
    const void* W_mlp2       = d_in[11];
    const void* W_mlp3       = d_in[12];
    const void* W_down_s     = d_in[13];
    const void* W_down_v     = d_in[14];

    char* ws = (char*)d_ws;
    size_t off = 0;
    __hip_bfloat16* hbuf = (__hip_bfloat16*)(ws + off); off += (size_t)N_NODES * 256 * 2;
    float* agg_s = (float*)(ws + off);                  off += (size_t)N_NODES * 128 * 4;
    float* agg_v = (float*)(ws + off);                  off += (size_t)N_NODES * 384 * 4;
    int* cnt    = (int*)(ws + off);                     off += (size_t)N_NODES * 4;
    int* offs   = (int*)(ws + off);                     off += (size_t)(N_NODES + 4) * 4;
    int* cursor = (int*)(ws + off);                     off += (size_t)N_NODES * 4;
    int* sorted = (int*)(ws + off);                     off += (size_t)N_EDGES * 4;
    int* flag   = (int*)(ws + off);

    detect_kernel<<<dim3(1), dim3(64), 0, stream>>>((const unsigned short*)W_up_s, flag);
    hipMemsetAsync(cnt, 0, (size_t)N_NODES * 4, stream);

    hist_kernel<<<dim3(1875), dim3(256), 0, stream>>>(receivers, cnt);
    scan_kernel<<<dim3(1), dim3(1024), 0, stream>>>(cnt, offs, cursor);
    scatter_kernel<<<dim3(1875), dim3(256), 0, stream>>>(receivers, cursor, sorted);

    node_up_kernel<true><<<dim3(2500), dim3(256), 0, stream>>>(
        node_scalars, node_vectors, W_up_s, W_up_v, hbuf, flag);
    node_up_kernel<false><<<dim3(2500), dim3(256), 0, stream>>>(
        node_scalars, node_vectors, W_up_s, W_up_v, hbuf, flag);

    agg_kernel<true><<<dim3(10000), dim3(256), 0, stream>>>(
        vectors, senders, sorted, offs, W_mlp1, W_mlp2, W_mlp3, hbuf, agg_s, agg_v, flag);
    agg_kernel<false><<<dim3(10000), dim3(256), 0, stream>>>(
        vectors, senders, sorted, offs, W_mlp1, W_mlp2, W_mlp3, hbuf, agg_s, agg_v, flag);

    node_final_kernel<true><<<dim3(2500), dim3(256), 0, stream>>>(
        node_scalars, node_vectors, node_specie, W_skip_s, W_skip_v,
        W_down_s, W_down_v, agg_s, agg_v, d_out, flag);
    node_final_kernel<false><<<dim3(2500), dim3(256), 0, stream>>>(
        node_scalars, node_vectors, node_specie, W_skip_s, W_skip_v,
        W_down_s, W_down_v, agg_s, agg_v, d_out, flag);
}

// Round 4
// 1109.649 us; speedup vs baseline: 2.3204x; 1.5967x over previous
//
#include <hip/hip_runtime.h>
#include <hip/hip_bf16.h>

#define N_NODES 40000
#define N_EDGES 480000
#define SEG 4
#define SEG_E (N_EDGES / SEG)      // 120000
#define SEG_TILES (SEG_E / 16)     // 7500

typedef short bf16x8 __attribute__((ext_vector_type(8)));
typedef float f32x4 __attribute__((ext_vector_type(4)));

__device__ __forceinline__ float bf2f(__hip_bfloat16 x) { return __bfloat162float(x); }

__device__ __forceinline__ float lane_bcast(float v, int i) {
    union { float f; int i; } u; u.f = v;
    int r = __builtin_amdgcn_readlane(u.i, i);
    union { int i; float f; } w; w.i = r; return w.f;
}

__device__ __forceinline__ float swishf(float x) { return x / (1.0f + __expf(-x)); }

__device__ __forceinline__ float bflo(unsigned u) { union { unsigned u; float f; } w; w.u = u << 16; return w.f; }
__device__ __forceinline__ float bfhi(unsigned u) { union { unsigned u; float f; } w; w.u = u & 0xffff0000u; return w.f; }
__device__ __forceinline__ float bfu(unsigned short u) { union { unsigned u; float f; } w; w.u = ((unsigned)u) << 16; return w.f; }

__device__ __forceinline__ unsigned short f2bf_bits(float x) {
    union { __hip_bfloat16 h; unsigned short u; } c; c.h = __float2bfloat16(x); return c.u;
}

__constant__ const float INV8 = 0.35355339059327373f;
__constant__ const float INV64 = 0.125f;
__constant__ const float INV128 = 0.08838834764831845f;
__constant__ const float INV_NN = 0.2886751345948129f;   // 1/sqrt(12)
__constant__ const float SQRT2 = 1.4142135623730951f;
__constant__ const float SQRT3 = 1.7320508075688772f;
__constant__ const float INV_SQRT3 = 0.5773502691896258f;
__constant__ const float PI_F = 3.14159265358979323846f;

template<bool F32>
__device__ __forceinline__ float LD(const void* p, int i) {
    if constexpr (F32) return ((const float*)p)[i];
    else return bf2f(((const __hip_bfloat16*)p)[i]);
}
template<bool F32>
__device__ __forceinline__ void ST(void* p, int i, float v) {
    if constexpr (F32) ((float*)p)[i] = v;
    else ((__hip_bfloat16*)p)[i] = __float2bfloat16(v);
}

// ---------------- dtype probe ----------------
__global__ void detect_kernel(const unsigned short* __restrict__ w, int* __restrict__ flag) {
    int lane = threadIdx.x;
    int cnt = 0;
    for (int i = lane; i < 2048; i += 64) {
        unsigned e = (w[2 * i] >> 7) & 0xFF;
        if (e >= 110 && e <= 133) cnt++;
    }
    #pragma unroll
    for (int off = 32; off > 0; off >>= 1) cnt += __shfl_down(cnt, off, 64);
    if (lane == 0) *flag = (cnt > 1024) ? 1 : 0;
}

// ---------------- counting sort by receiver ----------------
__global__ __launch_bounds__(256) void hist_kernel(const int* __restrict__ receivers,
                                                   int* __restrict__ cnt) {
    int e = blockIdx.x * 256 + threadIdx.x;
    if (e < N_EDGES) atomicAdd(&cnt[receivers[e]], 1);
}

__global__ __launch_bounds__(1024) void scan_kernel(const int* __restrict__ cnt,
                                                    int* __restrict__ offs,
                                                    int* __restrict__ cursor) {
    __shared__ int part[1024];
    int t = threadIdx.x;
    const int CH = 40;
    int base = t * CH;
    int s = 0;
    #pragma unroll 4
    for (int i = 0; i < CH; i++) {
        int idx = base + i;
        if (idx < N_NODES) s += cnt[idx];
    }
    part[t] = s;
    __syncthreads();
    for (int off = 1; off < 1024; off <<= 1) {
        int tmp = (t >= off) ? part[t - off] : 0;
        __syncthreads();
        part[t] += tmp;
        __syncthreads();
    }
    int run = part[t] - s;
    for (int i = 0; i < CH; i++) {
        int idx = base + i;
        if (idx < N_NODES) {
            offs[idx] = run;
            cursor[idx] = run;
            run += cnt[idx];
        }
    }
    if (t == 1023) offs[N_NODES] = part[1023];
}

__global__ __launch_bounds__(256) void scatter_kernel(const int* __restrict__ receivers,
                                                      const int* __restrict__ senders,
                                                      int* __restrict__ cursor,
                                                      int* __restrict__ sorted_eid,
                                                      int* __restrict__ sorted_snd) {
    int e = blockIdx.x * 256 + threadIdx.x;
    if (e < N_EDGES) {
        int p = atomicAdd(&cursor[receivers[e]], 1);
        sorted_eid[p] = e;
        sorted_snd[p] = senders[e];
    }
}

// ---------------- Kernel A: per-node up-projection ----------------
// hbuf[n][l][0..3] = {h_s[l], h_v.x[l], h_v.y[l], h_v.z[l]} packed bf16
template<bool F32>
__global__ __launch_bounds__(256) void node_up_kernel(
    const void* __restrict__ node_scalars,
    const void* __restrict__ node_vectors,
    const void* __restrict__ W_up_s,
    const void* __restrict__ W_up_v,
    unsigned short* __restrict__ hbuf,       // [N,64,4] bf16 bits
    const int* __restrict__ flag)
{
    if ((*flag != 0) == F32) return;
    __shared__ float WsL[4096];
    __shared__ float WvL[4096];
    int tid = threadIdx.x;
    for (int idx = tid; idx < 4096; idx += 256) {
        WsL[idx] = LD<F32>(W_up_s, idx);
        WvL[idx] = LD<F32>(W_up_v, idx);
    }
    __syncthreads();
    int wave = tid >> 6, lane = tid & 63;
    for (int n = blockIdx.x * 4 + wave; n < N_NODES; n += gridDim.x * 4) {
        float s_in = LD<F32>(node_scalars, n * 64 + lane);
        float v0 = LD<F32>(node_vectors, n * 192 + lane * 3 + 0);
        float v1 = LD<F32>(node_vectors, n * 192 + lane * 3 + 1);
        float v2 = LD<F32>(node_vectors, n * 192 + lane * 3 + 2);
        float hs = 0.f, hv0 = 0.f, hv1 = 0.f, hv2 = 0.f;
        for (int i = 0; i < 64; i++) {
            float si = lane_bcast(s_in, i);
            hs = fmaf(si, WsL[i * 64 + lane], hs);
            float w = WvL[i * 64 + lane];
            hv0 = fmaf(lane_bcast(v0, i), w, hv0);
            hv1 = fmaf(lane_bcast(v1, i), w, hv1);
            hv2 = fmaf(lane_bcast(v2, i), w, hv2);
        }
        uint2 pk;
        pk.x = f2bf_bits(hs * INV64) | ((unsigned)f2bf_bits(hv0 * INV64) << 16);
        pk.y = f2bf_bits(hv1 * INV64) | ((unsigned)f2bf_bits(hv2 * INV64) << 16);
        *(uint2*)(hbuf + (size_t)n * 256 + lane * 4) = pk;
    }
}

// ---------------- Kernel M: MFMA edge MLP (one 16-edge tile per wave) ----------------
template<bool F32>
__global__ __launch_bounds__(512) void mlp_kernel(
    const void* __restrict__ vectors,
    const int* __restrict__ sorted_eid,
    const void* __restrict__ W1,             // [8,64]
    const void* __restrict__ W2,             // [64,64]
    const void* __restrict__ W3,             // [64,256]
    unsigned short* __restrict__ mixseg,     // [SEG_E,256] bf16 bits
    unsigned short* __restrict__ yq,         // [E,4] bf16 bits (global p)
    int p_lo,
    const int* __restrict__ flag)
{
    if ((*flag != 0) == F32) return;
    __shared__ unsigned short W3T[256 * 72];   // W3T[o][k], stride 72 (align+bank pad)
    __shared__ unsigned short W2T[64 * 72];    // W2T[o][k]
    __shared__ unsigned short hbl[8 * 64 * 17];
    int tid = threadIdx.x;
    for (int idx = tid; idx < 16384; idx += 512) {
        int o = idx & 255, k = idx >> 8;
        W3T[o * 72 + k] = f2bf_bits(LD<F32>(W3, k * 256 + o));
    }
    for (int idx = tid; idx < 4096; idx += 512) {
        int o = idx & 63, k = idx >> 6;
        W2T[o * 72 + k] = f2bf_bits(LD<F32>(W2, k * 64 + o));
    }
    __syncthreads();
    int wave = tid >> 6, lane = tid & 63;
    int m = lane & 15, q = lane >> 4;
    int tile = blockIdx.x * 8 + wave;
    if (tile >= SEG_TILES) return;
    int p = p_lo + tile * 16 + m;

    // geometry for edge p (all quads compute redundantly; quad0's rb feeds MFMA)
    int e = sorted_eid[p];
    float vx = LD<F32>(vectors, e * 3 + 0);
    float vy = LD<F32>(vectors, e * 3 + 1);
    float vz = LD<F32>(vectors, e * 3 + 2);
    float len2 = vx * vx + vy * vy + vz * vz;
    float len = sqrtf(len2);
    float Yx = 0.f, Yy = 0.f, Yz = 0.f;
    float rb[8];
    if (len > 0.f) {
        float inv = 1.f / len;
        Yx = SQRT3 * vx * inv; Yy = SQRT3 * vy * inv; Yz = SQRT3 * vz * inv;
        float x6 = len2 * len2 * len2;
        float env = (len < 1.f) ? fmaf(x6, fmaf(len, fmaf(len, -21.f, 48.f), -28.f), 1.f) : 0.f;
        float c = SQRT2 * inv * env;
        #pragma unroll
        for (int k = 0; k < 8; k++) rb[k] = c * __sinf((float)(k + 1) * PI_F * len);
    } else {
        #pragma unroll
        for (int k = 0; k < 8; k++) rb[k] = 0.f;
    }
    if (q == 0) {
        uint2 yw;
        yw.x = f2bf_bits(Yx) | ((unsigned)f2bf_bits(Yy) << 16);
        yw.y = f2bf_bits(Yz);
        *(uint2*)(yq + (size_t)p * 4) = yw;
    }

    f32x4 zero4 = {0.f, 0.f, 0.f, 0.f};
    unsigned short* hb = hbl + wave * (64 * 17);

    // ---- layer1: h1[o][edge] = rb @ W1, K=8 (zero-padded to 32) ----
    bf16x8 b_rb;
    #pragma unroll
    for (int j = 0; j < 8; j++) b_rb[j] = (q == 0) ? (short)f2bf_bits(rb[j]) : (short)0;
    #pragma unroll
    for (int t = 0; t < 4; t++) {
        bf16x8 a;
        #pragma unroll
        for (int j = 0; j < 8; j++) a[j] = 0;
        if (q == 0) {
            #pragma unroll
            for (int j = 0; j < 8; j++)
                a[j] = (short)f2bf_bits(LD<F32>(W1, j * 64 + 16 * t + m));
        }
        f32x4 c = __builtin_amdgcn_mfma_f32_16x16x32_bf16(a, b_rb, zero4, 0, 0, 0);
        #pragma unroll
        for (int r = 0; r < 4; r++)
            hb[(16 * t + 4 * q + r) * 17 + m] = f2bf_bits(swishf(c[r] * INV8));
    }
    // ---- repack h1 -> B fragments ----
    bf16x8 b2[2];
    #pragma unroll
    for (int h = 0; h < 2; h++)
        #pragma unroll
        for (int j = 0; j < 8; j++)
            b2[h][j] = (short)hb[(32 * h + 8 * q + j) * 17 + m];
    // ---- layer2: K=64 ----
    #pragma unroll
    for (int t = 0; t < 4; t++) {
        bf16x8 a0 = *(const bf16x8*)(W2T + (16 * t + m) * 72 + 8 * q);
        bf16x8 a1 = *(const bf16x8*)(W2T + (16 * t + m) * 72 + 32 + 8 * q);
        f32x4 c = __builtin_amdgcn_mfma_f32_16x16x32_bf16(a0, b2[0], zero4, 0, 0, 0);
        c = __builtin_amdgcn_mfma_f32_16x16x32_bf16(a1, b2[1], c, 0, 0, 0);
        #pragma unroll
        for (int r = 0; r < 4; r++)
            hb[(16 * t + 4 * q + r) * 17 + m] = f2bf_bits(swishf(c[r] * INV64));
    }
    bf16x8 b3[2];
    #pragma unroll
    for (int h = 0; h < 2; h++)
        #pragma unroll
        for (int j = 0; j < 8; j++)
            b3[h][j] = (short)hb[(32 * h + 8 * q + j) * 17 + m];
    // ---- layer3: 256 outputs, 16 M-tiles ----
    size_t rowbase = ((size_t)(tile * 16 + m)) * 256;
    #pragma unroll
    for (int t3 = 0; t3 < 16; t3++) {
        bf16x8 a0 = *(const bf16x8*)(W3T + (16 * t3 + m) * 72 + 8 * q);
        bf16x8 a1 = *(const bf16x8*)(W3T + (16 * t3 + m) * 72 + 32 + 8 * q);
        f32x4 c = __builtin_amdgcn_mfma_f32_16x16x32_bf16(a0, b3[0], zero4, 0, 0, 0);
        c = __builtin_amdgcn_mfma_f32_16x16x32_bf16(a1, b3[1], c, 0, 0, 0);
        uint2 v;
        v.x = f2bf_bits(c[0] * INV64) | ((unsigned)f2bf_bits(c[1] * INV64) << 16);
        v.y = f2bf_bits(c[2] * INV64) | ((unsigned)f2bf_bits(c[3] * INV64) << 16);
        *(uint2*)(mixseg + rowbase + 16 * t3 + 4 * q) = v;
    }
}

// ---------------- Kernel B: lean per-node aggregation (segmented) ----------------
__global__ __launch_bounds__(256) void agg_kernel(
    const unsigned short* __restrict__ hbuf,      // [N,64,4]
    const int* __restrict__ sorted_snd,
    const unsigned short* __restrict__ mixseg,    // [SEG_E,256]
    const unsigned short* __restrict__ yq,        // [E,4]
    const int* __restrict__ offs,
    float* __restrict__ agg_s,
    float* __restrict__ agg_v,
    int slo, int shi)
{
    int tid = threadIdx.x, wave = tid >> 6, lane = tid & 63;
    int n = blockIdx.x * 4 + wave;
    if (n >= N_NODES) return;
    int beg = __builtin_amdgcn_readfirstlane(offs[n]);
    int end = __builtin_amdgcn_readfirstlane(offs[n + 1]);
    int lo = beg > slo ? beg : slo;
    int hi = end < shi ? end : shi;
    bool owner = (beg >= slo && beg < shi) || (beg >= shi && shi == N_EDGES);
    if (!owner && hi <= lo) return;
    float* aS = agg_s + (size_t)n * 128;
    float* aV = agg_v + (size_t)n * 384;
    float s0, s1, v0, v1, v2, v3, v4, v5;
    if (owner) {
        s0 = s1 = v0 = v1 = v2 = v3 = v4 = v5 = 0.f;
    } else {
        s0 = aS[lane]; s1 = aS[64 + lane];
        v0 = aV[lane]; v1 = aV[64 + lane]; v2 = aV[128 + lane];
        v3 = aV[192 + lane]; v4 = aV[256 + lane]; v5 = aV[320 + lane];
    }
    for (int p = lo; p < hi; p++) {
        int snd = __builtin_amdgcn_readfirstlane(sorted_snd[p]);
        uint2 hbv = *(const uint2*)(hbuf + (size_t)snd * 256 + lane * 4);
        float m_s = bflo(hbv.x), mv0 = bfhi(hbv.x);
        float mv1 = bflo(hbv.y), mv2 = bfhi(hbv.y);
        const unsigned short* mp = mixseg + (size_t)(p - slo) * 256;
        float mix0 = bfu(mp[lane]);
        float mix1 = bfu(mp[64 + lane]);
        float mix2 = bfu(mp[128 + lane]);
        float mix3 = bfu(mp[192 + lane]);
        uint2 yw = *(const uint2*)(yq + (size_t)p * 4);
        float Yx = bflo(yw.x), Yy = bfhi(yw.x), Yz = bflo(yw.y);
        float tp0 = (mv0 * Yx + mv1 * Yy + mv2 * Yz) * INV_SQRT3;
        s0 = fmaf(m_s, mix0, s0);
        s1 = fmaf(tp0, mix1, s1);
        float t1 = m_s * mix3;
        v0 = fmaf(mv0, mix2, v0);
        v1 = fmaf(t1, Yx, v1);
        v2 = fmaf(mv1, mix2, v2);
        v3 = fmaf(t1, Yy, v3);
        v4 = fmaf(mv2, mix2, v4);
        v5 = fmaf(t1, Yz, v5);
    }
    aS[lane] = s0; aS[64 + lane] = s1;
    aV[lane] = v0; aV[64 + lane] = v1; aV[128 + lane] = v2;
    aV[192 + lane] = v3; aV[256 + lane] = v4; aV[320 + lane] = v5;
}

// ---------------- Kernel C: per-node down-projection + skip + gate ----------------
template<bool F32>
__global__ __launch_bounds__(256) void node_final_kernel(
    const void* __restrict__ node_scalars,
    const void* __restrict__ node_vectors,
    const int* __restrict__ node_specie,
    const void* __restrict__ W_skip_s,       // [5,64,128]
    const void* __restrict__ W_skip_v,       // [5,64,64]
    const void* __restrict__ W_down_s,       // [128,128]
    const void* __restrict__ W_down_v,       // [128,64]
    const float* __restrict__ agg_s,
    const float* __restrict__ agg_v,
    void* __restrict__ out,
    const int* __restrict__ flag)
{
    if ((*flag != 0) == F32) return;
    __shared__ float WdsL[16384];
    __shared__ float WdvL[8192];
    int tid = threadIdx.x;
    for (int idx = tid; idx < 16384; idx += 256) WdsL[idx] = LD<F32>(W_down_s, idx);
    for (int idx = tid; idx < 8192; idx += 256) WdvL[idx] = LD<F32>(W_down_v, idx);
    __syncthreads();
    int wave = tid >> 6, lane = tid & 63;
    const float SC = INV128 * INV_NN;
    for (int n = blockIdx.x * 4 + wave; n < N_NODES; n += gridDim.x * 4) {
        int sp = node_specie[n];
        const float* ags = agg_s + (size_t)n * 128;
        const float* agv = agg_v + (size_t)n * 384;
        float as0 = ags[lane], as1 = ags[64 + lane];
        float av00 = agv[lane],       av01 = agv[64 + lane];
        float av10 = agv[128 + lane], av11 = agv[192 + lane];
        float av20 = agv[256 + lane], av21 = agv[320 + lane];
        float s_in = LD<F32>(node_scalars, n * 64 + lane);
        float vi0 = LD<F32>(node_vectors, n * 192 + lane * 3 + 0);
        float vi1 = LD<F32>(node_vectors, n * 192 + lane * 3 + 1);
        float vi2 = LD<F32>(node_vectors, n * 192 + lane * 3 + 2);
        int wss_off = sp * 8192, wsv_off = sp * 4096;
        float ds0 = 0.f, ds1 = 0.f, dv0 = 0.f, dv1 = 0.f, dv2 = 0.f;
        float scs0 = 0.f, scs1 = 0.f, scv0 = 0.f, scv1 = 0.f, scv2 = 0.f;
        for (int i = 0; i < 64; i++) {
            float a0 = lane_bcast(as0, i), a1 = lane_bcast(as1, i);
            ds0 = fmaf(a0, WdsL[i * 128 + lane], ds0);
            ds0 = fmaf(a1, WdsL[(64 + i) * 128 + lane], ds0);
            ds1 = fmaf(a0, WdsL[i * 128 + 64 + lane], ds1);
            ds1 = fmaf(a1, WdsL[(64 + i) * 128 + 64 + lane], ds1);
            float w0 = WdvL[i * 64 + lane], w1 = WdvL[(64 + i) * 64 + lane];
            dv0 = fmaf(lane_bcast(av00, i), w0, dv0); dv0 = fmaf(lane_bcast(av01, i), w1, dv0);
            dv1 = fmaf(lane_bcast(av10, i), w0, dv1); dv1 = fmaf(lane_bcast(av11, i), w1, dv1);
            dv2 = fmaf(lane_bcast(av20, i), w0, dv2); dv2 = fmaf(lane_bcast(av21, i), w1, dv2);
            float si = lane_bcast(s_in, i);
            scs0 = fmaf(si, LD<F32>(W_skip_s, wss_off + i * 128 + lane), scs0);
            scs1 = fmaf(si, LD<F32>(W_skip_s, wss_off + i * 128 + 64 + lane), scs1);
            float wv = LD<F32>(W_skip_v, wsv_off + i * 64 + lane);
            scv0 = fmaf(lane_bcast(vi0, i), wv, scv0);
            scv1 = fmaf(lane_bcast(vi1, i), wv, scv1);
            scv2 = fmaf(lane_bcast(vi2, i), wv, scv2);
        }
        float d_s0 = ds0 * SC + scs0 * INV64;
        float d_s1 = ds1 * SC + scs1 * INV64;
        float outs = swishf(d_s0);
        float g = swishf(d_s1);
        float o0 = (dv0 * SC + scv0 * INV64) * g;
        float o1 = (dv1 * SC + scv1 * INV64) * g;
        float o2 = (dv2 * SC + scv2 * INV64) * g;
        int ob = n * 256;
        ST<F32>(out, ob + lane, outs);
        ST<F32>(out, ob + 64 + lane * 3 + 0, o0);
        ST<F32>(out, ob + 64 + lane * 3 + 1, o1);
        ST<F32>(out, ob + 64 + lane * 3 + 2, o2);
    }
}

extern "C" void kernel_launch(void* const* d_in, const int* in_sizes, int n_in,
                              void* d_out, int out_size, void* d_ws, size_t ws_size,
                              hipStream_t stream) {
    const void* vectors      = d_in[0];
    const void* node_scalars = d_in[1];
    const void* node_vectors = d_in[2];
    const int* node_specie   = (const int*)d_in[3];
    const int* senders       = (const int*)d_in[4];
    const int* receivers     = (const int*)d_in[5];
    const void* W_up_s       = d_in[6];
    const void* W_up_v       = d_in[7];
    const void* W_skip_s     = d_in[8];
    const void* W_skip_v     = d_in[9];
    const void* W_mlp1       = d_in[10];
    const void* W_mlp2       = d_in[11];
    const void* W_mlp3       = d_in[12];
    const void* W_down_s     = d_in[13];
    const void* W_down_v     = d_in[14];

    char* ws = (char*)d_ws;
    size_t off = 0;
    auto alloc = [&](size_t bytes) { void* p = ws + off; off += (bytes + 255) & ~(size_t)255; return p; };
    unsigned short* hbuf   = (unsigned short*)alloc((size_t)N_NODES * 256 * 2);
    float* agg_s           = (float*)alloc((size_t)N_NODES * 128 * 4);
    float* agg_v           = (float*)alloc((size_t)N_NODES * 384 * 4);
    unsigned short* mixseg = (unsigned short*)alloc((size_t)SEG_E * 256 * 2);
    unsigned short* yq     = (unsigned short*)alloc((size_t)N_EDGES * 4 * 2);
    int* cnt    = (int*)alloc((size_t)N_NODES * 4);
    int* offs   = (int*)alloc((size_t)(N_NODES + 1) * 4);
    int* cursor = (int*)alloc((size_t)N_NODES * 4);
    int* sorted = (int*)alloc((size_t)N_EDGES * 4);
    int* sorted_snd = (int*)alloc((size_t)N_EDGES * 4);
    int* flag   = (int*)alloc(4);

    detect_kernel<<<dim3(1), dim3(64), 0, stream>>>((const unsigned short*)W_up_s, flag);
    hipMemsetAsync(cnt, 0, (size_t)N_NODES * 4, stream);

    hist_kernel<<<dim3(1875), dim3(256), 0, stream>>>(receivers, cnt);
    scan_kernel<<<dim3(1), dim3(1024), 0, stream>>>(cnt, offs, cursor);
    scatter_kernel<<<dim3(1875), dim3(256), 0, stream>>>(receivers, senders, cursor, sorted, sorted_snd);

    node_up_kernel<true><<<dim3(2500), dim3(256), 0, stream>>>(
        node_scalars, node_vectors, W_up_s, W_up_v, hbuf, flag);
    node_up_kernel<false><<<dim3(2500), dim3(256), 0, stream>>>(
        node_scalars, node_vectors, W_up_s, W_up_v, hbuf, flag);

    const int MLP_BLOCKS = (SEG_TILES + 7) / 8;   // 938
    for (int s = 0; s < SEG; s++) {
        int p_lo = s * SEG_E;
        mlp_kernel<true><<<dim3(MLP_BLOCKS), dim3(512), 0, stream>>>(
            vectors, sorted, W_mlp1, W_mlp2, W_mlp3, mixseg, yq, p_lo, flag);
        mlp_kernel<false><<<dim3(MLP_BLOCKS), dim3(512), 0, stream>>>(
            vectors, sorted, W_mlp1, W_mlp2, W_mlp3, mixseg, yq, p_lo, flag);
        agg_kernel<<<dim3(10000), dim3(256), 0, stream>>>(
            hbuf, sorted_snd, mixseg, yq, offs, agg_s, agg_v, p_lo, p_lo + SEG_E);
    }

    node_final_kernel<true><<<dim3(2500), dim3(256), 0, stream>>>(
        node_scalars, node_vectors, node_specie, W_skip_s, W_skip_v,
        W_down_s, W_down_v, agg_s, agg_v, d_out, flag);
    node_final_kernel<false><<<dim3(2500), dim3(256), 0, stream>>>(
        node_scalars, node_vectors, node_specie, W_skip_s, W_skip_v,
        W_down_s, W_down_v, agg_s, agg_v, d_out, flag);
}

// Round 5
// 1070.624 us; speedup vs baseline: 2.4049x; 1.0365x over previous
//
#include <hip/hip_runtime.h>
#include <hip/hip_bf16.h>

#define N_NODES 40000
#define N_EDGES 480000
#define SEG 4
#define SEG_E (N_EDGES / SEG)      // 120000
#define SEG_TILES (SEG_E / 16)     // 7500

typedef short bf16x8 __attribute__((ext_vector_type(8)));
typedef float f32x4 __attribute__((ext_vector_type(4)));

__device__ __forceinline__ float bf2f(__hip_bfloat16 x) { return __bfloat162float(x); }

__device__ __forceinline__ float lane_bcast(float v, int i) {
    union { float f; int i; } u; u.f = v;
    int r = __builtin_amdgcn_readlane(u.i, i);
    union { int i; float f; } w; w.i = r; return w.f;
}

__device__ __forceinline__ float swishf(float x) { return x / (1.0f + __expf(-x)); }

__device__ __forceinline__ float bflo(unsigned u) { union { unsigned u; float f; } w; w.u = u << 16; return w.f; }
__device__ __forceinline__ float bfhi(unsigned u) { union { unsigned u; float f; } w; w.u = u & 0xffff0000u; return w.f; }
__device__ __forceinline__ float bfu(unsigned short u) { union { unsigned u; float f; } w; w.u = ((unsigned)u) << 16; return w.f; }

__device__ __forceinline__ unsigned short f2bf_bits(float x) {
    union { __hip_bfloat16 h; unsigned short u; } c; c.h = __float2bfloat16(x); return c.u;
}

__constant__ const float INV8 = 0.35355339059327373f;
__constant__ const float INV64 = 0.125f;
__constant__ const float INV128 = 0.08838834764831845f;
__constant__ const float INV_NN = 0.2886751345948129f;   // 1/sqrt(12)
__constant__ const float SQRT2 = 1.4142135623730951f;
__constant__ const float SQRT3 = 1.7320508075688772f;
__constant__ const float INV_SQRT3 = 0.5773502691896258f;
__constant__ const float PI_F = 3.14159265358979323846f;

template<bool F32>
__device__ __forceinline__ float LD(const void* p, int i) {
    if constexpr (F32) return ((const float*)p)[i];
    else return bf2f(((const __hip_bfloat16*)p)[i]);
}
template<bool F32>
__device__ __forceinline__ void ST(void* p, size_t i, float v) {
    if constexpr (F32) ((float*)p)[i] = v;
    else ((__hip_bfloat16*)p)[i] = __float2bfloat16(v);
}

// ---------------- dtype probe ----------------
__global__ void detect_kernel(const unsigned short* __restrict__ w, int* __restrict__ flag) {
    int lane = threadIdx.x;
    int cnt = 0;
    for (int i = lane; i < 2048; i += 64) {
        unsigned e = (w[2 * i] >> 7) & 0xFF;
        if (e >= 110 && e <= 133) cnt++;
    }
    #pragma unroll
    for (int off = 32; off > 0; off >>= 1) cnt += __shfl_down(cnt, off, 64);
    if (lane == 0) *flag = (cnt > 1024) ? 1 : 0;
}

// ---------------- counting sort of edges by receiver ----------------
__global__ __launch_bounds__(256) void hist_kernel(const int* __restrict__ receivers,
                                                   int* __restrict__ cnt) {
    int e = blockIdx.x * 256 + threadIdx.x;
    if (e < N_EDGES) atomicAdd(&cnt[receivers[e]], 1);
}

__global__ __launch_bounds__(1024) void scan_kernel(const int* __restrict__ cnt,
                                                    int* __restrict__ offs,
                                                    int* __restrict__ cursor) {
    __shared__ int part[1024];
    int t = threadIdx.x;
    const int CH = 40;
    int base = t * CH;
    int s = 0;
    #pragma unroll 4
    for (int i = 0; i < CH; i++) {
        int idx = base + i;
        if (idx < N_NODES) s += cnt[idx];
    }
    part[t] = s;
    __syncthreads();
    for (int off = 1; off < 1024; off <<= 1) {
        int tmp = (t >= off) ? part[t - off] : 0;
        __syncthreads();
        part[t] += tmp;
        __syncthreads();
    }
    int run = part[t] - s;
    for (int i = 0; i < CH; i++) {
        int idx = base + i;
        if (idx < N_NODES) {
            offs[idx] = run;
            cursor[idx] = run;
            run += cnt[idx];
        }
    }
    if (t == 1023) offs[N_NODES] = part[1023];
}

__global__ __launch_bounds__(256) void scatter_kernel(const int* __restrict__ receivers,
                                                      const int* __restrict__ senders,
                                                      int* __restrict__ cursor,
                                                      int* __restrict__ sorted_eid,
                                                      int* __restrict__ sorted_snd) {
    int e = blockIdx.x * 256 + threadIdx.x;
    if (e < N_EDGES) {
        int p = atomicAdd(&cursor[receivers[e]], 1);
        sorted_eid[p] = e;
        sorted_snd[p] = senders[e];
    }
}

// ---------------- counting sort of nodes by species ----------------
__global__ __launch_bounds__(256) void hist5_kernel(const int* __restrict__ specie,
                                                    int* __restrict__ cnt5) {
    int n = blockIdx.x * 256 + threadIdx.x;
    if (n < N_NODES) atomicAdd(&cnt5[specie[n]], 1);
}

// tile_info[0..5] = block_base prefix (blocks of 4 tiles); tile_info[8+s] = tiles of species s
__global__ void scan5_kernel(const int* __restrict__ cnt5, int* __restrict__ sp_offs,
                             int* __restrict__ cursor5, int* __restrict__ tile_info) {
    if (threadIdx.x != 0 || blockIdx.x != 0) return;
    int run = 0, tb = 0;
    for (int s = 0; s < 5; s++) {
        sp_offs[s] = run; cursor5[s] = run;
        tile_info[s] = tb;
        int c = cnt5[s];
        int T = (c + 15) >> 4;
        tile_info[8 + s] = T;
        tb += (T + 3) >> 2;
        run += c;
    }
    sp_offs[5] = run;
    tile_info[5] = tb;
}

__global__ __launch_bounds__(256) void scatter5_kernel(const int* __restrict__ specie,
                                                       int* __restrict__ cursor5,
                                                       int* __restrict__ sorted_node) {
    int n = blockIdx.x * 256 + threadIdx.x;
    if (n < N_NODES) {
        int p = atomicAdd(&cursor5[specie[n]], 1);
        sorted_node[p] = n;
    }
}

// ---------------- Kernel A: per-node up-projection (+ bf16 input packing) ----------------
// hbuf[n][l][0..3] = {h_s, h_v.x, h_v.y, h_v.z} bf16; ns_b[n][64]; nv_t[c][n][64]
template<bool F32>
__global__ __launch_bounds__(256) void node_up_kernel(
    const void* __restrict__ node_scalars,
    const void* __restrict__ node_vectors,
    const void* __restrict__ W_up_s,
    const void* __restrict__ W_up_v,
    unsigned short* __restrict__ hbuf,
    unsigned short* __restrict__ ns_b,
    unsigned short* __restrict__ nv_t,
    const int* __restrict__ flag)
{
    if ((*flag != 0) == F32) return;
    __shared__ float WsL[4096];
    __shared__ float WvL[4096];
    int tid = threadIdx.x;
    for (int idx = tid; idx < 4096; idx += 256) {
        WsL[idx] = LD<F32>(W_up_s, idx);
        WvL[idx] = LD<F32>(W_up_v, idx);
    }
    __syncthreads();
    int wave = tid >> 6, lane = tid & 63;
    for (int n = blockIdx.x * 4 + wave; n < N_NODES; n += gridDim.x * 4) {
        float s_in = LD<F32>(node_scalars, n * 64 + lane);
        float v0 = LD<F32>(node_vectors, n * 192 + lane * 3 + 0);
        float v1 = LD<F32>(node_vectors, n * 192 + lane * 3 + 1);
        float v2 = LD<F32>(node_vectors, n * 192 + lane * 3 + 2);
        ns_b[(size_t)n * 64 + lane] = f2bf_bits(s_in);
        nv_t[(size_t)n * 64 + lane] = f2bf_bits(v0);
        nv_t[(size_t)N_NODES * 64 + (size_t)n * 64 + lane] = f2bf_bits(v1);
        nv_t[(size_t)N_NODES * 128 + (size_t)n * 64 + lane] = f2bf_bits(v2);
        float hs = 0.f, hv0 = 0.f, hv1 = 0.f, hv2 = 0.f;
        for (int i = 0; i < 64; i++) {
            float si = lane_bcast(s_in, i);
            hs = fmaf(si, WsL[i * 64 + lane], hs);
            float w = WvL[i * 64 + lane];
            hv0 = fmaf(lane_bcast(v0, i), w, hv0);
            hv1 = fmaf(lane_bcast(v1, i), w, hv1);
            hv2 = fmaf(lane_bcast(v2, i), w, hv2);
        }
        uint2 pk;
        pk.x = f2bf_bits(hs * INV64) | ((unsigned)f2bf_bits(hv0 * INV64) << 16);
        pk.y = f2bf_bits(hv1 * INV64) | ((unsigned)f2bf_bits(hv2 * INV64) << 16);
        *(uint2*)(hbuf + (size_t)n * 256 + lane * 4) = pk;
    }
}

// ---------------- Kernel M: MFMA edge MLP (one 16-edge tile per wave) ----------------
template<bool F32>
__global__ __launch_bounds__(512) void mlp_kernel(
    const void* __restrict__ vectors,
    const int* __restrict__ sorted_eid,
    const void* __restrict__ W1,             // [8,64]
    const void* __restrict__ W2,             // [64,64]
    const void* __restrict__ W3,             // [64,256]
    unsigned short* __restrict__ mixseg,     // [SEG_E,256] bf16 bits
    unsigned short* __restrict__ yq,         // [E,4] bf16 bits
    int p_lo,
    const int* __restrict__ flag)
{
    if ((*flag != 0) == F32) return;
    __shared__ unsigned short W3T[256 * 72];
    __shared__ unsigned short W2T[64 * 72];
    __shared__ unsigned short hbl[8 * 64 * 17];
    int tid = threadIdx.x;
    for (int idx = tid; idx < 16384; idx += 512) {
        int o = idx & 255, k = idx >> 8;
        W3T[o * 72 + k] = f2bf_bits(LD<F32>(W3, k * 256 + o));
    }
    for (int idx = tid; idx < 4096; idx += 512) {
        int o = idx & 63, k = idx >> 6;
        W2T[o * 72 + k] = f2bf_bits(LD<F32>(W2, k * 64 + o));
    }
    __syncthreads();
    int wave = tid >> 6, lane = tid & 63;
    int m = lane & 15, q = lane >> 4;
    int tile = blockIdx.x * 8 + wave;
    if (tile >= SEG_TILES) return;
    int p = p_lo + tile * 16 + m;

    int e = sorted_eid[p];
    float vx = LD<F32>(vectors, e * 3 + 0);
    float vy = LD<F32>(vectors, e * 3 + 1);
    float vz = LD<F32>(vectors, e * 3 + 2);
    float len2 = vx * vx + vy * vy + vz * vz;
    float len = sqrtf(len2);
    float Yx = 0.f, Yy = 0.f, Yz = 0.f;
    float rb[8];
    if (len > 0.f) {
        float inv = 1.f / len;
        Yx = SQRT3 * vx * inv; Yy = SQRT3 * vy * inv; Yz = SQRT3 * vz * inv;
        float x6 = len2 * len2 * len2;
        float env = (len < 1.f) ? fmaf(x6, fmaf(len, fmaf(len, -21.f, 48.f), -28.f), 1.f) : 0.f;
        float c = SQRT2 * inv * env;
        #pragma unroll
        for (int k = 0; k < 8; k++) rb[k] = c * __sinf((float)(k + 1) * PI_F * len);
    } else {
        #pragma unroll
        for (int k = 0; k < 8; k++) rb[k] = 0.f;
    }
    if (q == 0) {
        uint2 yw;
        yw.x = f2bf_bits(Yx) | ((unsigned)f2bf_bits(Yy) << 16);
        yw.y = f2bf_bits(Yz);
        *(uint2*)(yq + (size_t)p * 4) = yw;
    }

    f32x4 zero4 = {0.f, 0.f, 0.f, 0.f};
    unsigned short* hb = hbl + wave * (64 * 17);

    bf16x8 b_rb;
    #pragma unroll
    for (int j = 0; j < 8; j++) b_rb[j] = (q == 0) ? (short)f2bf_bits(rb[j]) : (short)0;
    #pragma unroll
    for (int t = 0; t < 4; t++) {
        bf16x8 a;
        #pragma unroll
        for (int j = 0; j < 8; j++) a[j] = 0;
        if (q == 0) {
            #pragma unroll
            for (int j = 0; j < 8; j++)
                a[j] = (short)f2bf_bits(LD<F32>(W1, j * 64 + 16 * t + m));
        }
        f32x4 c = __builtin_amdgcn_mfma_f32_16x16x32_bf16(a, b_rb, zero4, 0, 0, 0);
        #pragma unroll
        for (int r = 0; r < 4; r++)
            hb[(16 * t + 4 * q + r) * 17 + m] = f2bf_bits(swishf(c[r] * INV8));
    }
    bf16x8 b2[2];
    #pragma unroll
    for (int h = 0; h < 2; h++)
        #pragma unroll
        for (int j = 0; j < 8; j++)
            b2[h][j] = (short)hb[(32 * h + 8 * q + j) * 17 + m];
    #pragma unroll
    for (int t = 0; t < 4; t++) {
        bf16x8 a0 = *(const bf16x8*)(W2T + (16 * t + m) * 72 + 8 * q);
        bf16x8 a1 = *(const bf16x8*)(W2T + (16 * t + m) * 72 + 32 + 8 * q);
        f32x4 c = __builtin_amdgcn_mfma_f32_16x16x32_bf16(a0, b2[0], zero4, 0, 0, 0);
        c = __builtin_amdgcn_mfma_f32_16x16x32_bf16(a1, b2[1], c, 0, 0, 0);
        #pragma unroll
        for (int r = 0; r < 4; r++)
            hb[(16 * t + 4 * q + r) * 17 + m] = f2bf_bits(swishf(c[r] * INV64));
    }
    bf16x8 b3[2];
    #pragma unroll
    for (int h = 0; h < 2; h++)
        #pragma unroll
        for (int j = 0; j < 8; j++)
            b3[h][j] = (short)hb[(32 * h + 8 * q + j) * 17 + m];
    size_t rowbase = ((size_t)(tile * 16 + m)) * 256;
    #pragma unroll
    for (int t3 = 0; t3 < 16; t3++) {
        bf16x8 a0 = *(const bf16x8*)(W3T + (16 * t3 + m) * 72 + 8 * q);
        bf16x8 a1 = *(const bf16x8*)(W3T + (16 * t3 + m) * 72 + 32 + 8 * q);
        f32x4 c = __builtin_amdgcn_mfma_f32_16x16x32_bf16(a0, b3[0], zero4, 0, 0, 0);
        c = __builtin_amdgcn_mfma_f32_16x16x32_bf16(a1, b3[1], c, 0, 0, 0);
        uint2 v;
        v.x = f2bf_bits(c[0] * INV64) | ((unsigned)f2bf_bits(c[1] * INV64) << 16);
        v.y = f2bf_bits(c[2] * INV64) | ((unsigned)f2bf_bits(c[3] * INV64) << 16);
        *(uint2*)(mixseg + rowbase + 16 * t3 + 4 * q) = v;
    }
}

// ---------------- Kernel B: lean per-node aggregation (segmented, bf16 out) ----------------
__global__ __launch_bounds__(256) void agg_kernel(
    const unsigned short* __restrict__ hbuf,      // [N,64,4]
    const int* __restrict__ sorted_snd,
    const unsigned short* __restrict__ mixseg,    // [SEG_E,256]
    const unsigned short* __restrict__ yq,        // [E,4]
    const int* __restrict__ offs,
    unsigned short* __restrict__ agg_s_b,         // [N,128] bf16
    unsigned short* __restrict__ agg_v_b,         // [N,384] bf16
    int slo, int shi)
{
    int tid = threadIdx.x, wave = tid >> 6, lane = tid & 63;
    int n = blockIdx.x * 4 + wave;
    if (n >= N_NODES) return;
    int beg = __builtin_amdgcn_readfirstlane(offs[n]);
    int end = __builtin_amdgcn_readfirstlane(offs[n + 1]);
    int lo = beg > slo ? beg : slo;
    int hi = end < shi ? end : shi;
    bool owner = (beg >= slo && beg < shi) || (beg >= shi && shi == N_EDGES);
    if (!owner && hi <= lo) return;
    unsigned short* aS = agg_s_b + (size_t)n * 128;
    unsigned short* aV = agg_v_b + (size_t)n * 384;
    float s0, s1, v0, v1, v2, v3, v4, v5;
    if (owner) {
        s0 = s1 = v0 = v1 = v2 = v3 = v4 = v5 = 0.f;
    } else {
        s0 = bfu(aS[lane]); s1 = bfu(aS[64 + lane]);
        v0 = bfu(aV[lane]); v1 = bfu(aV[64 + lane]); v2 = bfu(aV[128 + lane]);
        v3 = bfu(aV[192 + lane]); v4 = bfu(aV[256 + lane]); v5 = bfu(aV[320 + lane]);
    }
    for (int p = lo; p < hi; p++) {
        int snd = __builtin_amdgcn_readfirstlane(sorted_snd[p]);
        uint2 hbv = *(const uint2*)(hbuf + (size_t)snd * 256 + lane * 4);
        float m_s = bflo(hbv.x), mv0 = bfhi(hbv.x);
        float mv1 = bflo(hbv.y), mv2 = bfhi(hbv.y);
        const unsigned short* mp = mixseg + (size_t)(p - slo) * 256;
        float mix0 = bfu(mp[lane]);
        float mix1 = bfu(mp[64 + lane]);
        float mix2 = bfu(mp[128 + lane]);
        float mix3 = bfu(mp[192 + lane]);
        uint2 yw = *(const uint2*)(yq + (size_t)p * 4);
        float Yx = bflo(yw.x), Yy = bfhi(yw.x), Yz = bflo(yw.y);
        float tp0 = (mv0 * Yx + mv1 * Yy + mv2 * Yz) * INV_SQRT3;
        s0 = fmaf(m_s, mix0, s0);
        s1 = fmaf(tp0, mix1, s1);
        float t1 = m_s * mix3;
        v0 = fmaf(mv0, mix2, v0);
        v1 = fmaf(t1, Yx, v1);
        v2 = fmaf(mv1, mix2, v2);
        v3 = fmaf(t1, Yy, v3);
        v4 = fmaf(mv2, mix2, v4);
        v5 = fmaf(t1, Yz, v5);
    }
    aS[lane] = f2bf_bits(s0); aS[64 + lane] = f2bf_bits(s1);
    aV[lane] = f2bf_bits(v0); aV[64 + lane] = f2bf_bits(v1); aV[128 + lane] = f2bf_bits(v2);
    aV[192 + lane] = f2bf_bits(v3); aV[256 + lane] = f2bf_bits(v4); aV[320 + lane] = f2bf_bits(v5);
}

// ---------------- Kernel C: MFMA down-projection + skip + gate ----------------
// One 16-node tile per wave; nodes species-sorted so each block has one species.
// A (LDS, bf16): As[o][k] o<128: k<128 = Wds[k][o]*SC, k>=128 = Wss[sp][k-128][o]*INV64
//                Av[o][k] o<64:  k<128 = Wdv[k][o]*SC, k>=128 = Wsv[sp][k-128][o]*INV64
template<bool F32>
__global__ __launch_bounds__(256) void node_final_kernel(
    const void* __restrict__ W_skip_s,       // [5,64,128]
    const void* __restrict__ W_skip_v,       // [5,64,64]
    const void* __restrict__ W_down_s,       // [128,128]
    const void* __restrict__ W_down_v,       // [128,64]
    const unsigned short* __restrict__ ns_b,      // [N,64]
    const unsigned short* __restrict__ nv_t,      // [3,N,64]
    const unsigned short* __restrict__ agg_s_b,   // [N,128]
    const unsigned short* __restrict__ agg_v_b,   // [N,384]
    const int* __restrict__ sorted_node,
    const int* __restrict__ sp_offs,         // [6]
    const int* __restrict__ tile_info,       // [16]
    void* __restrict__ out,
    const int* __restrict__ flag)
{
    if ((*flag != 0) == F32) return;
    int b = blockIdx.x;
    if (b >= tile_info[5]) return;           // block-uniform
    __shared__ unsigned short As[128 * 200];
    __shared__ unsigned short Av[64 * 200];
    int sp = 0;
    #pragma unroll
    for (int s = 1; s < 5; s++) if (b >= tile_info[s]) sp = s;
    const float SC = INV128 * INV_NN;
    int tid = threadIdx.x;
    for (int idx = tid; idx < 128 * 192; idx += 256) {
        int o = idx / 192, k = idx - o * 192;
        float w = (k < 128) ? LD<F32>(W_down_s, k * 128 + o) * SC
                            : LD<F32>(W_skip_s, sp * 8192 + (k - 128) * 128 + o) * INV64;
        As[o * 200 + k] = f2bf_bits(w);
    }
    for (int idx = tid; idx < 64 * 192; idx += 256) {
        int o = idx / 192, k = idx - o * 192;
        float w = (k < 128) ? LD<F32>(W_down_v, k * 64 + o) * SC
                            : LD<F32>(W_skip_v, sp * 4096 + (k - 128) * 64 + o) * INV64;
        Av[o * 200 + k] = f2bf_bits(w);
    }
    __syncthreads();
    int wave = tid >> 6, lane = tid & 63;
    int m = lane & 15, q = lane >> 4;
    int T = tile_info[8 + sp];
    int tl = (b - tile_info[sp]) * 4 + wave;
    if (tl >= T) return;                     // after the only __syncthreads
    int row = sp_offs[sp] + tl * 16;
    int cnt = sp_offs[sp + 1] - row; if (cnt > 16) cnt = 16;
    int mm = (m < cnt) ? m : 0;
    int node = sorted_node[row + mm];

    // B fragments (16-B bf16 loads)
    bf16x8 bs[6];
    {
        const unsigned short* a = agg_s_b + (size_t)node * 128;
        #pragma unroll
        for (int f = 0; f < 4; f++) bs[f] = *(const bf16x8*)(a + f * 32 + q * 8);
        const unsigned short* s = ns_b + (size_t)node * 64;
        #pragma unroll
        for (int f = 0; f < 2; f++) bs[4 + f] = *(const bf16x8*)(s + f * 32 + q * 8);
    }
    bf16x8 bv[3][6];
    #pragma unroll
    for (int c = 0; c < 3; c++) {
        const unsigned short* a = agg_v_b + (size_t)node * 384 + c * 128;
        #pragma unroll
        for (int f = 0; f < 4; f++) bv[c][f] = *(const bf16x8*)(a + f * 32 + q * 8);
        const unsigned short* s = nv_t + (size_t)c * N_NODES * 64 + (size_t)node * 64;
        #pragma unroll
        for (int f = 0; f < 2; f++) bv[c][4 + f] = *(const bf16x8*)(s + f * 32 + q * 8);
    }
    f32x4 z4 = {0.f, 0.f, 0.f, 0.f};
    // gates: ds tiles 4..7
    float gate[4][4];
    #pragma unroll
    for (int t = 0; t < 4; t++) {
        f32x4 c = z4;
        #pragma unroll
        for (int f = 0; f < 6; f++) {
            bf16x8 a = *(const bf16x8*)(As + (16 * (4 + t) + m) * 200 + f * 32 + q * 8);
            c = __builtin_amdgcn_mfma_f32_16x16x32_bf16(a, bs[f], c, 0, 0, 0);
        }
        #pragma unroll
        for (int r = 0; r < 4; r++) gate[t][r] = swishf(c[r]);
    }
    // out scalars: ds tiles 0..3
    #pragma unroll
    for (int t = 0; t < 4; t++) {
        f32x4 c = z4;
        #pragma unroll
        for (int f = 0; f < 6; f++) {
            bf16x8 a = *(const bf16x8*)(As + (16 * t + m) * 200 + f * 32 + q * 8);
            c = __builtin_amdgcn_mfma_f32_16x16x32_bf16(a, bs[f], c, 0, 0, 0);
        }
        if (m < cnt) {
            size_t base = (size_t)node * 256 + 16 * t + 4 * q;
            if constexpr (F32) {
                float4 o4 = { swishf(c[0]), swishf(c[1]), swishf(c[2]), swishf(c[3]) };
                *(float4*)((float*)out + base) = o4;
            } else {
                uint2 o2;
                o2.x = f2bf_bits(swishf(c[0])) | ((unsigned)f2bf_bits(swishf(c[1])) << 16);
                o2.y = f2bf_bits(swishf(c[2])) | ((unsigned)f2bf_bits(swishf(c[3])) << 16);
                *(uint2*)((unsigned short*)out + base) = o2;
            }
        }
    }
    // vectors: dv tiles 0..3 × 3 channels, gated
    #pragma unroll
    for (int t = 0; t < 4; t++) {
        f32x4 c0 = z4, c1 = z4, c2 = z4;
        #pragma unroll
        for (int f = 0; f < 6; f++) {
            bf16x8 a = *(const bf16x8*)(Av + (16 * t + m) * 200 + f * 32 + q * 8);
            c0 = __builtin_amdgcn_mfma_f32_16x16x32_bf16(a, bv[0][f], c0, 0, 0, 0);
            c1 = __builtin_amdgcn_mfma_f32_16x16x32_bf16(a, bv[1][f], c1, 0, 0, 0);
            c2 = __builtin_amdgcn_mfma_f32_16x16x32_bf16(a, bv[2][f], c2, 0, 0, 0);
        }
        if (m < cnt) {
            #pragma unroll
            for (int r = 0; r < 4; r++) {
                float g = gate[t][r];
                int o = 16 * t + 4 * q + r;
                size_t base = (size_t)node * 256 + 64 + (size_t)o * 3;
                ST<F32>(out, base + 0, c0[r] * g);
                ST<F32>(out, base + 1, c1[r] * g);
                ST<F32>(out, base + 2, c2[r] * g);
            }
        }
    }
}

extern "C" void kernel_launch(void* const* d_in, const int* in_sizes, int n_in,
                              void* d_out, int out_size, void* d_ws, size_t ws_size,
                              hipStream_t stream) {
    const void* vectors      = d_in[0];
    const void* node_scalars = d_in[1];
    const void* node_vectors = d_in[2];
    const int* node_specie   = (const int*)d_in[3];
    const int* senders       = (const int*)d_in[4];
    const int* receivers     = (const int*)d_in[5];
    const void* W_up_s       = d_in[6];
    const void* W_up_v       = d_in[7];
    const void* W_skip_s     = d_in[8];
    const void* W_skip_v     = d_in[9];
    const void* W_mlp1       = d_in[10];
    const void* W_mlp2       = d_in[11];
    const void* W_mlp3       = d_in[12];
    const void* W_down_s     = d_in[13];
    const void* W_down_v     = d_in[14];

    char* ws = (char*)d_ws;
    size_t off = 0;
    auto alloc = [&](size_t bytes) { void* p = ws + off; off += (bytes + 255) & ~(size_t)255; return p; };
    unsigned short* hbuf     = (unsigned short*)alloc((size_t)N_NODES * 256 * 2);
    unsigned short* ns_b     = (unsigned short*)alloc((size_t)N_NODES * 64 * 2);
    unsigned short* nv_t     = (unsigned short*)alloc((size_t)N_NODES * 192 * 2);
    unsigned short* agg_s_b  = (unsigned short*)alloc((size_t)N_NODES * 128 * 2);
    unsigned short* agg_v_b  = (unsigned short*)alloc((size_t)N_NODES * 384 * 2);
    unsigned short* mixseg   = (unsigned short*)alloc((size_t)SEG_E * 256 * 2);
    unsigned short* yq       = (unsigned short*)alloc((size_t)N_EDGES * 4 * 2);
    int* cnt        = (int*)alloc((size_t)(N_NODES + 8) * 4);   // cnt + cnt5 (contiguous, one memset)
    int* cnt5       = cnt + N_NODES;
    int* offs       = (int*)alloc((size_t)(N_NODES + 1) * 4);
    int* cursor     = (int*)alloc((size_t)N_NODES * 4);
    int* sorted     = (int*)alloc((size_t)N_EDGES * 4);
    int* sorted_snd = (int*)alloc((size_t)N_EDGES * 4);
    int* sorted_node= (int*)alloc((size_t)N_NODES * 4);
    int* sp_offs    = (int*)alloc(16 * 4);
    int* cursor5    = (int*)alloc(16 * 4);
    int* tile_info  = (int*)alloc(16 * 4);
    int* flag       = (int*)alloc(4);

    detect_kernel<<<dim3(1), dim3(64), 0, stream>>>((const unsigned short*)W_up_s, flag);
    hipMemsetAsync(cnt, 0, (size_t)(N_NODES + 8) * 4, stream);

    hist_kernel<<<dim3(1875), dim3(256), 0, stream>>>(receivers, cnt);
    scan_kernel<<<dim3(1), dim3(1024), 0, stream>>>(cnt, offs, cursor);
    scatter_kernel<<<dim3(1875), dim3(256), 0, stream>>>(receivers, senders, cursor, sorted, sorted_snd);

    hist5_kernel<<<dim3(157), dim3(256), 0, stream>>>(node_specie, cnt5);
    scan5_kernel<<<dim3(1), dim3(64), 0, stream>>>(cnt5, sp_offs, cursor5, tile_info);
    scatter5_kernel<<<dim3(157), dim3(256), 0, stream>>>(node_specie, cursor5, sorted_node);

    node_up_kernel<true><<<dim3(2500), dim3(256), 0, stream>>>(
        node_scalars, node_vectors, W_up_s, W_up_v, hbuf, ns_b, nv_t, flag);
    node_up_kernel<false><<<dim3(2500), dim3(256), 0, stream>>>(
        node_scalars, node_vectors, W_up_s, W_up_v, hbuf, ns_b, nv_t, flag);

    const int MLP_BLOCKS = (SEG_TILES + 7) / 8;   // 938
    for (int s = 0; s < SEG; s++) {
        int p_lo = s * SEG_E;
        mlp_kernel<true><<<dim3(MLP_BLOCKS), dim3(512), 0, stream>>>(
            vectors, sorted, W_mlp1, W_mlp2, W_mlp3, mixseg, yq, p_lo, flag);
        mlp_kernel<false><<<dim3(MLP_BLOCKS), dim3(512), 0, stream>>>(
            vectors, sorted, W_mlp1, W_mlp2, W_mlp3, mixseg, yq, p_lo, flag);
        agg_kernel<<<dim3(10000), dim3(256), 0, stream>>>(
            hbuf, sorted_snd, mixseg, yq, offs, agg_s_b, agg_v_b, p_lo, p_lo + SEG_E);
    }

    // max blocks: ceil(2500/4)+5 = 630; launch 640 (extras exit on tile_info[5])
    node_final_kernel<true><<<dim3(640), dim3(256), 0, stream>>>(
        W_skip_s, W_skip_v, W_down_s, W_down_v, ns_b, nv_t, agg_s_b, agg_v_b,
        sorted_node, sp_offs, tile_info, d_out, flag);
    node_final_kernel<false><<<dim3(640), dim3(256), 0, stream>>>(
        W_skip_s, W_skip_v, W_down_s, W_down_v, ns_b, nv_t, agg_s_b, agg_v_b,
        sorted_node, sp_offs, tile_info, d_out, flag);
}

// Round 6
// 766.925 us; speedup vs baseline: 3.3573x; 1.3960x over previous
//
#include <hip/hip_runtime.h>
#include <hip/hip_bf16.h>

#define N_NODES 40000
#define N_EDGES 480000
#define SEG 4
#define SEG_E (N_EDGES / SEG)      // 120000
#define SEG_TILES (SEG_E / 16)     // 7500

typedef short bf16x8 __attribute__((ext_vector_type(8)));
typedef float f32x4 __attribute__((ext_vector_type(4)));

__device__ __forceinline__ float bf2f(__hip_bfloat16 x) { return __bfloat162float(x); }

__device__ __forceinline__ float lane_bcast(float v, int i) {
    union { float f; int i; } u; u.f = v;
    int r = __builtin_amdgcn_readlane(u.i, i);
    union { int i; float f; } w; w.i = r; return w.f;
}

__device__ __forceinline__ float swishf(float x) { return x / (1.0f + __expf(-x)); }

__device__ __forceinline__ float bflo(unsigned u) { union { unsigned u; float f; } w; w.u = u << 16; return w.f; }
__device__ __forceinline__ float bfhi(unsigned u) { union { unsigned u; float f; } w; w.u = u & 0xffff0000u; return w.f; }
__device__ __forceinline__ float bfu(unsigned short u) { union { unsigned u; float f; } w; w.u = ((unsigned)u) << 16; return w.f; }

__device__ __forceinline__ unsigned short f2bf_bits(float x) {
    union { __hip_bfloat16 h; unsigned short u; } c; c.h = __float2bfloat16(x); return c.u;
}

__constant__ const float INV8 = 0.35355339059327373f;
__constant__ const float INV64 = 0.125f;
__constant__ const float INV128 = 0.08838834764831845f;
__constant__ const float INV_NN = 0.2886751345948129f;   // 1/sqrt(12)
__constant__ const float SQRT2 = 1.4142135623730951f;
__constant__ const float SQRT3 = 1.7320508075688772f;
__constant__ const float INV_SQRT3 = 0.5773502691896258f;
__constant__ const float PI_F = 3.14159265358979323846f;

template<bool F32>
__device__ __forceinline__ float LD(const void* p, int i) {
    if constexpr (F32) return ((const float*)p)[i];
    else return bf2f(((const __hip_bfloat16*)p)[i]);
}
template<bool F32>
__device__ __forceinline__ void ST(void* p, size_t i, float v) {
    if constexpr (F32) ((float*)p)[i] = v;
    else ((__hip_bfloat16*)p)[i] = __float2bfloat16(v);
}

// ---------------- dtype probe ----------------
__global__ void detect_kernel(const unsigned short* __restrict__ w, int* __restrict__ flag) {
    int lane = threadIdx.x;
    int cnt = 0;
    for (int i = lane; i < 2048; i += 64) {
        unsigned e = (w[2 * i] >> 7) & 0xFF;
        if (e >= 110 && e <= 133) cnt++;
    }
    #pragma unroll
    for (int off = 32; off > 0; off >>= 1) cnt += __shfl_down(cnt, off, 64);
    if (lane == 0) *flag = (cnt > 1024) ? 1 : 0;
}

// ---------------- counting sort of edges by receiver ----------------
__global__ __launch_bounds__(256) void hist_kernel(const int* __restrict__ receivers,
                                                   int* __restrict__ cnt) {
    int e = blockIdx.x * 256 + threadIdx.x;
    if (e < N_EDGES) atomicAdd(&cnt[receivers[e]], 1);
}

__global__ __launch_bounds__(1024) void scan_kernel(const int* __restrict__ cnt,
                                                    int* __restrict__ offs,
                                                    int* __restrict__ cursor) {
    __shared__ int part[1024];
    int t = threadIdx.x;
    const int CH = 40;
    int base = t * CH;
    int s = 0;
    #pragma unroll 4
    for (int i = 0; i < CH; i++) {
        int idx = base + i;
        if (idx < N_NODES) s += cnt[idx];
    }
    part[t] = s;
    __syncthreads();
    for (int off = 1; off < 1024; off <<= 1) {
        int tmp = (t >= off) ? part[t - off] : 0;
        __syncthreads();
        part[t] += tmp;
        __syncthreads();
    }
    int run = part[t] - s;
    for (int i = 0; i < CH; i++) {
        int idx = base + i;
        if (idx < N_NODES) {
            offs[idx] = run;
            cursor[idx] = run;
            run += cnt[idx];
        }
    }
    if (t == 1023) offs[N_NODES] = part[1023];
}

__global__ __launch_bounds__(256) void scatter_kernel(const int* __restrict__ receivers,
                                                      const int* __restrict__ senders,
                                                      int* __restrict__ cursor,
                                                      int* __restrict__ sorted_eid,
                                                      int* __restrict__ sorted_snd) {
    int e = blockIdx.x * 256 + threadIdx.x;
    if (e < N_EDGES) {
        int p = atomicAdd(&cursor[receivers[e]], 1);
        sorted_eid[p] = e;
        sorted_snd[p] = senders[e];
    }
}

// ---------------- counting sort of nodes by species (wave-aggregated atomics) ----------------
// 5-bin atomics serialize (~4.7 ns each): per-lane atomics cost 190 us. Ballot-aggregate
// to ONE leader atomic per wave per species: 3125 atomics total (~10 us).
__global__ __launch_bounds__(256) void hist5_kernel(const int* __restrict__ specie,
                                                    int* __restrict__ cnt5) {
    int n = blockIdx.x * 256 + threadIdx.x;
    int lane = threadIdx.x & 63;
    int sp = (n < N_NODES) ? specie[n] : -1;
    #pragma unroll
    for (int s = 0; s < 5; s++) {
        unsigned long long mask = __ballot(sp == s);
        if (mask != 0ull) {                       // wave-uniform
            int leader = __builtin_ctzll(mask);
            if (lane == leader) atomicAdd(&cnt5[s], __popcll(mask));
        }
    }
}

// tile_info[0..5] = block_base prefix (blocks of 4 tiles); tile_info[8+s] = tiles of species s
__global__ void scan5_kernel(const int* __restrict__ cnt5, int* __restrict__ sp_offs,
                             int* __restrict__ cursor5, int* __restrict__ tile_info) {
    if (threadIdx.x != 0 || blockIdx.x != 0) return;
    int run = 0, tb = 0;
    for (int s = 0; s < 5; s++) {
        sp_offs[s] = run; cursor5[s] = run;
        tile_info[s] = tb;
        int c = cnt5[s];
        int T = (c + 15) >> 4;
        tile_info[8 + s] = T;
        tb += (T + 3) >> 2;
        run += c;
    }
    sp_offs[5] = run;
    tile_info[5] = tb;
}

__global__ __launch_bounds__(256) void scatter5_kernel(const int* __restrict__ specie,
                                                       int* __restrict__ cursor5,
                                                       int* __restrict__ sorted_node) {
    int n = blockIdx.x * 256 + threadIdx.x;
    int lane = threadIdx.x & 63;
    int sp = (n < N_NODES) ? specie[n] : -1;
    #pragma unroll
    for (int s = 0; s < 5; s++) {
        unsigned long long mask = __ballot(sp == s);
        if (mask != 0ull) {                       // wave-uniform
            int leader = __builtin_ctzll(mask);
            int base = 0;
            if (lane == leader) base = atomicAdd(&cursor5[s], __popcll(mask));
            base = __shfl(base, leader);
            if (sp == s) {
                int prefix = __popcll(mask & ((1ull << lane) - 1ull));
                sorted_node[base + prefix] = n;
            }
        }
    }
}

// ---------------- Kernel A: per-node up-projection (+ bf16 input packing) ----------------
template<bool F32>
__global__ __launch_bounds__(256) void node_up_kernel(
    const void* __restrict__ node_scalars,
    const void* __restrict__ node_vectors,
    const void* __restrict__ W_up_s,
    const void* __restrict__ W_up_v,
    unsigned short* __restrict__ hbuf,
    unsigned short* __restrict__ ns_b,
    unsigned short* __restrict__ nv_t,
    const int* __restrict__ flag)
{
    if ((*flag != 0) == F32) return;
    __shared__ float WsL[4096];
    __shared__ float WvL[4096];
    int tid = threadIdx.x;
    for (int idx = tid; idx < 4096; idx += 256) {
        WsL[idx] = LD<F32>(W_up_s, idx);
        WvL[idx] = LD<F32>(W_up_v, idx);
    }
    __syncthreads();
    int wave = tid >> 6, lane = tid & 63;
    for (int n = blockIdx.x * 4 + wave; n < N_NODES; n += gridDim.x * 4) {
        float s_in = LD<F32>(node_scalars, n * 64 + lane);
        float v0 = LD<F32>(node_vectors, n * 192 + lane * 3 + 0);
        float v1 = LD<F32>(node_vectors, n * 192 + lane * 3 + 1);
        float v2 = LD<F32>(node_vectors, n * 192 + lane * 3 + 2);
        ns_b[(size_t)n * 64 + lane] = f2bf_bits(s_in);
        nv_t[(size_t)n * 64 + lane] = f2bf_bits(v0);
        nv_t[(size_t)N_NODES * 64 + (size_t)n * 64 + lane] = f2bf_bits(v1);
        nv_t[(size_t)N_NODES * 128 + (size_t)n * 64 + lane] = f2bf_bits(v2);
        float hs = 0.f, hv0 = 0.f, hv1 = 0.f, hv2 = 0.f;
        for (int i = 0; i < 64; i++) {
            float si = lane_bcast(s_in, i);
            hs = fmaf(si, WsL[i * 64 + lane], hs);
            float w = WvL[i * 64 + lane];
            hv0 = fmaf(lane_bcast(v0, i), w, hv0);
            hv1 = fmaf(lane_bcast(v1, i), w, hv1);
            hv2 = fmaf(lane_bcast(v2, i), w, hv2);
        }
        uint2 pk;
        pk.x = f2bf_bits(hs * INV64) | ((unsigned)f2bf_bits(hv0 * INV64) << 16);
        pk.y = f2bf_bits(hv1 * INV64) | ((unsigned)f2bf_bits(hv2 * INV64) << 16);
        *(uint2*)(hbuf + (size_t)n * 256 + lane * 4) = pk;
    }
}

// ---------------- Kernel M: MFMA edge MLP (one 16-edge tile per wave) ----------------
template<bool F32>
__global__ __launch_bounds__(512) void mlp_kernel(
    const void* __restrict__ vectors,
    const int* __restrict__ sorted_eid,
    const void* __restrict__ W1,             // [8,64]
    const void* __restrict__ W2,             // [64,64]
    const void* __restrict__ W3,             // [64,256]
    unsigned short* __restrict__ mixseg,     // [SEG_E,256] bf16 bits
    unsigned short* __restrict__ yq,         // [E,4] bf16 bits
    int p_lo,
    const int* __restrict__ flag)
{
    if ((*flag != 0) == F32) return;
    __shared__ unsigned short W3T[256 * 72];
    __shared__ unsigned short W2T[64 * 72];
    __shared__ unsigned short hbl[8 * 64 * 17];
    int tid = threadIdx.x;
    for (int idx = tid; idx < 16384; idx += 512) {
        int o = idx & 255, k = idx >> 8;
        W3T[o * 72 + k] = f2bf_bits(LD<F32>(W3, k * 256 + o));
    }
    for (int idx = tid; idx < 4096; idx += 512) {
        int o = idx & 63, k = idx >> 6;
        W2T[o * 72 + k] = f2bf_bits(LD<F32>(W2, k * 64 + o));
    }
    __syncthreads();
    int wave = tid >> 6, lane = tid & 63;
    int m = lane & 15, q = lane >> 4;
    int tile = blockIdx.x * 8 + wave;
    if (tile >= SEG_TILES) return;
    int p = p_lo + tile * 16 + m;

    int e = sorted_eid[p];
    float vx = LD<F32>(vectors, e * 3 + 0);
    float vy = LD<F32>(vectors, e * 3 + 1);
    float vz = LD<F32>(vectors, e * 3 + 2);
    float len2 = vx * vx + vy * vy + vz * vz;
    float len = sqrtf(len2);
    float Yx = 0.f, Yy = 0.f, Yz = 0.f;
    float rb[8];
    if (len > 0.f) {
        float inv = 1.f / len;
        Yx = SQRT3 * vx * inv; Yy = SQRT3 * vy * inv; Yz = SQRT3 * vz * inv;
        float x6 = len2 * len2 * len2;
        float env = (len < 1.f) ? fmaf(x6, fmaf(len, fmaf(len, -21.f, 48.f), -28.f), 1.f) : 0.f;
        float c = SQRT2 * inv * env;
        #pragma unroll
        for (int k = 0; k < 8; k++) rb[k] = c * __sinf((float)(k + 1) * PI_F * len);
    } else {
        #pragma unroll
        for (int k = 0; k < 8; k++) rb[k] = 0.f;
    }
    if (q == 0) {
        uint2 yw;
        yw.x = f2bf_bits(Yx) | ((unsigned)f2bf_bits(Yy) << 16);
        yw.y = f2bf_bits(Yz);
        *(uint2*)(yq + (size_t)p * 4) = yw;
    }

    f32x4 zero4 = {0.f, 0.f, 0.f, 0.f};
    unsigned short* hb = hbl + wave * (64 * 17);

    bf16x8 b_rb;
    #pragma unroll
    for (int j = 0; j < 8; j++) b_rb[j] = (q == 0) ? (short)f2bf_bits(rb[j]) : (short)0;
    #pragma unroll
    for (int t = 0; t < 4; t++) {
        bf16x8 a;
        #pragma unroll
        for (int j = 0; j < 8; j++) a[j] = 0;
        if (q == 0) {
            #pragma unroll
            for (int j = 0; j < 8; j++)
                a[j] = (short)f2bf_bits(LD<F32>(W1, j * 64 + 16 * t + m));
        }
        f32x4 c = __builtin_amdgcn_mfma_f32_16x16x32_bf16(a, b_rb, zero4, 0, 0, 0);
        #pragma unroll
        for (int r = 0; r < 4; r++)
            hb[(16 * t + 4 * q + r) * 17 + m] = f2bf_bits(swishf(c[r] * INV8));
    }
    bf16x8 b2[2];
    #pragma unroll
    for (int h = 0; h < 2; h++)
        #pragma unroll
        for (int j = 0; j < 8; j++)
            b2[h][j] = (short)hb[(32 * h + 8 * q + j) * 17 + m];
    #pragma unroll
    for (int t = 0; t < 4; t++) {
        bf16x8 a0 = *(const bf16x8*)(W2T + (16 * t + m) * 72 + 8 * q);
        bf16x8 a1 = *(const bf16x8*)(W2T + (16 * t + m) * 72 + 32 + 8 * q);
        f32x4 c = __builtin_amdgcn_mfma_f32_16x16x32_bf16(a0, b2[0], zero4, 0, 0, 0);
        c = __builtin_amdgcn_mfma_f32_16x16x32_bf16(a1, b2[1], c, 0, 0, 0);
        #pragma unroll
        for (int r = 0; r < 4; r++)
            hb[(16 * t + 4 * q + r) * 17 + m] = f2bf_bits(swishf(c[r] * INV64));
    }
    bf16x8 b3[2];
    #pragma unroll
    for (int h = 0; h < 2; h++)
        #pragma unroll
        for (int j = 0; j < 8; j++)
            b3[h][j] = (short)hb[(32 * h + 8 * q + j) * 17 + m];
    size_t rowbase = ((size_t)(tile * 16 + m)) * 256;
    #pragma unroll
    for (int t3 = 0; t3 < 16; t3++) {
        bf16x8 a0 = *(const bf16x8*)(W3T + (16 * t3 + m) * 72 + 8 * q);
        bf16x8 a1 = *(const bf16x8*)(W3T + (16 * t3 + m) * 72 + 32 + 8 * q);
        f32x4 c = __builtin_amdgcn_mfma_f32_16x16x32_bf16(a0, b3[0], zero4, 0, 0, 0);
        c = __builtin_amdgcn_mfma_f32_16x16x32_bf16(a1, b3[1], c, 0, 0, 0);
        uint2 v;
        v.x = f2bf_bits(c[0] * INV64) | ((unsigned)f2bf_bits(c[1] * INV64) << 16);
        v.y = f2bf_bits(c[2] * INV64) | ((unsigned)f2bf_bits(c[3] * INV64) << 16);
        *(uint2*)(mixseg + rowbase + 16 * t3 + 4 * q) = v;
    }
}

// ---------------- Kernel B: lean per-node aggregation (segmented, bf16 out) ----------------
__global__ __launch_bounds__(256) void agg_kernel(
    const unsigned short* __restrict__ hbuf,      // [N,64,4]
    const int* __restrict__ sorted_snd,
    const unsigned short* __restrict__ mixseg,    // [SEG_E,256]
    const unsigned short* __restrict__ yq,        // [E,4]
    const int* __restrict__ offs,
    unsigned short* __restrict__ agg_s_b,         // [N,128] bf16
    unsigned short* __restrict__ agg_v_b,         // [N,384] bf16
    int slo, int shi)
{
    int tid = threadIdx.x, wave = tid >> 6, lane = tid & 63;
    int n = blockIdx.x * 4 + wave;
    if (n >= N_NODES) return;
    int beg = __builtin_amdgcn_readfirstlane(offs[n]);
    int end = __builtin_amdgcn_readfirstlane(offs[n + 1]);
    int lo = beg > slo ? beg : slo;
    int hi = end < shi ? end : shi;
    bool owner = (beg >= slo && beg < shi) || (beg >= shi && shi == N_EDGES);
    if (!owner && hi <= lo) return;
    unsigned short* aS = agg_s_b + (size_t)n * 128;
    unsigned short* aV = agg_v_b + (size_t)n * 384;
    float s0, s1, v0, v1, v2, v3, v4, v5;
    if (owner) {
        s0 = s1 = v0 = v1 = v2 = v3 = v4 = v5 = 0.f;
    } else {
        s0 = bfu(aS[lane]); s1 = bfu(aS[64 + lane]);
        v0 = bfu(aV[lane]); v1 = bfu(aV[64 + lane]); v2 = bfu(aV[128 + lane]);
        v3 = bfu(aV[192 + lane]); v4 = bfu(aV[256 + lane]); v5 = bfu(aV[320 + lane]);
    }
    for (int p = lo; p < hi; p++) {
        int snd = __builtin_amdgcn_readfirstlane(sorted_snd[p]);
        uint2 hbv = *(const uint2*)(hbuf + (size_t)snd * 256 + lane * 4);
        float m_s = bflo(hbv.x), mv0 = bfhi(hbv.x);
        float mv1 = bflo(hbv.y), mv2 = bfhi(hbv.y);
        const unsigned short* mp = mixseg + (size_t)(p - slo) * 256;
        float mix0 = bfu(mp[lane]);
        float mix1 = bfu(mp[64 + lane]);
        float mix2 = bfu(mp[128 + lane]);
        float mix3 = bfu(mp[192 + lane]);
        uint2 yw = *(const uint2*)(yq + (size_t)p * 4);
        float Yx = bflo(yw.x), Yy = bfhi(yw.x), Yz = bflo(yw.y);
        float tp0 = (mv0 * Yx + mv1 * Yy + mv2 * Yz) * INV_SQRT3;
        s0 = fmaf(m_s, mix0, s0);
        s1 = fmaf(tp0, mix1, s1);
        float t1 = m_s * mix3;
        v0 = fmaf(mv0, mix2, v0);
        v1 = fmaf(t1, Yx, v1);
        v2 = fmaf(mv1, mix2, v2);
        v3 = fmaf(t1, Yy, v3);
        v4 = fmaf(mv2, mix2, v4);
        v5 = fmaf(t1, Yz, v5);
    }
    aS[lane] = f2bf_bits(s0); aS[64 + lane] = f2bf_bits(s1);
    aV[lane] = f2bf_bits(v0); aV[64 + lane] = f2bf_bits(v1); aV[128 + lane] = f2bf_bits(v2);
    aV[192 + lane] = f2bf_bits(v3); aV[256 + lane] = f2bf_bits(v4); aV[320 + lane] = f2bf_bits(v5);
}

// ---------------- Kernel C: MFMA down-projection + skip + gate ----------------
template<bool F32>
__global__ __launch_bounds__(256) void node_final_kernel(
    const void* __restrict__ W_skip_s,       // [5,64,128]
    const void* __restrict__ W_skip_v,       // [5,64,64]
    const void* __restrict__ W_down_s,       // [128,128]
    const void* __restrict__ W_down_v,       // [128,64]
    const unsigned short* __restrict__ ns_b,      // [N,64]
    const unsigned short* __restrict__ nv_t,      // [3,N,64]
    const unsigned short* __restrict__ agg_s_b,   // [N,128]
    const unsigned short* __restrict__ agg_v_b,   // [N,384]
    const int* __restrict__ sorted_node,
    const int* __restrict__ sp_offs,         // [6]
    const int* __restrict__ tile_info,       // [16]
    void* __restrict__ out,
    const int* __restrict__ flag)
{
    if ((*flag != 0) == F32) return;
    int b = blockIdx.x;
    if (b >= tile_info[5]) return;           // block-uniform
    __shared__ unsigned short As[128 * 200];
    __shared__ unsigned short Av[64 * 200];
    int sp = 0;
    #pragma unroll
    for (int s = 1; s < 5; s++) if (b >= tile_info[s]) sp = s;
    const float SC = INV128 * INV_NN;
    int tid = threadIdx.x;
    for (int idx = tid; idx < 128 * 192; idx += 256) {
        int o = idx / 192, k = idx - o * 192;
        float w = (k < 128) ? LD<F32>(W_down_s, k * 128 + o) * SC
                            : LD<F32>(W_skip_s, sp * 8192 + (k - 128) * 128 + o) * INV64;
        As[o * 200 + k] = f2bf_bits(w);
    }
    for (int idx = tid; idx < 64 * 192; idx += 256) {
        int o = idx / 192, k = idx - o * 192;
        float w = (k < 128) ? LD<F32>(W_down_v, k * 64 + o) * SC
                            : LD<F32>(W_skip_v, sp * 4096 + (k - 128) * 64 + o) * INV64;
        Av[o * 200 + k] = f2bf_bits(w);
    }
    __syncthreads();
    int wave = tid >> 6, lane = tid & 63;
    int m = lane & 15, q = lane >> 4;
    int T = tile_info[8 + sp];
    int tl = (b - tile_info[sp]) * 4 + wave;
    if (tl >= T) return;                     // after the only __syncthreads
    int row = sp_offs[sp] + tl * 16;
    int cnt = sp_offs[sp + 1] - row; if (cnt > 16) cnt = 16;
    int mm = (m < cnt) ? m : 0;
    int node = sorted_node[row + mm];

    bf16x8 bs[6];
    {
        const unsigned short* a = agg_s_b + (size_t)node * 128;
        #pragma unroll
        for (int f = 0; f < 4; f++) bs[f] = *(const bf16x8*)(a + f * 32 + q * 8);
        const unsigned short* s = ns_b + (size_t)node * 64;
        #pragma unroll
        for (int f = 0; f < 2; f++) bs[4 + f] = *(const bf16x8*)(s + f * 32 + q * 8);
    }
    bf16x8 bv[3][6];
    #pragma unroll
    for (int c = 0; c < 3; c++) {
        const unsigned short* a = agg_v_b + (size_t)node * 384 + c * 128;
        #pragma unroll
        for (int f = 0; f < 4; f++) bv[c][f] = *(const bf16x8*)(a + f * 32 + q * 8);
        const unsigned short* s = nv_t + (size_t)c * N_NODES * 64 + (size_t)node * 64;
        #pragma unroll
        for (int f = 0; f < 2; f++) bv[c][4 + f] = *(const bf16x8*)(s + f * 32 + q * 8);
    }
    f32x4 z4 = {0.f, 0.f, 0.f, 0.f};
    float gate[4][4];
    #pragma unroll
    for (int t = 0; t < 4; t++) {
        f32x4 c = z4;
        #pragma unroll
        for (int f = 0; f < 6; f++) {
            bf16x8 a = *(const bf16x8*)(As + (16 * (4 + t) + m) * 200 + f * 32 + q * 8);
            c = __builtin_amdgcn_mfma_f32_16x16x32_bf16(a, bs[f], c, 0, 0, 0);
        }
        #pragma unroll
        for (int r = 0; r < 4; r++) gate[t][r] = swishf(c[r]);
    }
    #pragma unroll
    for (int t = 0; t < 4; t++) {
        f32x4 c = z4;
        #pragma unroll
        for (int f = 0; f < 6; f++) {
            bf16x8 a = *(const bf16x8*)(As + (16 * t + m) * 200 + f * 32 + q * 8);
            c = __builtin_amdgcn_mfma_f32_16x16x32_bf16(a, bs[f], c, 0, 0, 0);
        }
        if (m < cnt) {
            size_t base = (size_t)node * 256 + 16 * t + 4 * q;
            if constexpr (F32) {
                float4 o4 = { swishf(c[0]), swishf(c[1]), swishf(c[2]), swishf(c[3]) };
                *(float4*)((float*)out + base) = o4;
            } else {
                uint2 o2;
                o2.x = f2bf_bits(swishf(c[0])) | ((unsigned)f2bf_bits(swishf(c[1])) << 16);
                o2.y = f2bf_bits(swishf(c[2])) | ((unsigned)f2bf_bits(swishf(c[3])) << 16);
                *(uint2*)((unsigned short*)out + base) = o2;
            }
        }
    }
    #pragma unroll
    for (int t = 0; t < 4; t++) {
        f32x4 c0 = z4, c1 = z4, c2 = z4;
        #pragma unroll
        for (int f = 0; f < 6; f++) {
            bf16x8 a = *(const bf16x8*)(Av + (16 * t + m) * 200 + f * 32 + q * 8);
            c0 = __builtin_amdgcn_mfma_f32_16x16x32_bf16(a, bv[0][f], c0, 0, 0, 0);
            c1 = __builtin_amdgcn_mfma_f32_16x16x32_bf16(a, bv[1][f], c1, 0, 0, 0);
            c2 = __builtin_amdgcn_mfma_f32_16x16x32_bf16(a, bv[2][f], c2, 0, 0, 0);
        }
        if (m < cnt) {
            #pragma unroll
            for (int r = 0; r < 4; r++) {
                float g = gate[t][r];
                int o = 16 * t + 4 * q + r;
                size_t base = (size_t)node * 256 + 64 + (size_t)o * 3;
                ST<F32>(out, base + 0, c0[r] * g);
                ST<F32>(out, base + 1, c1[r] * g);
                ST<F32>(out, base + 2, c2[r] * g);
            }
        }
    }
}

extern "C" void kernel_launch(void* const* d_in, const int* in_sizes, int n_in,
                              void* d_out, int out_size, void* d_ws, size_t ws_size,
                              hipStream_t stream) {
    const void* vectors      = d_in[0];
    const void* node_scalars = d_in[1];
    const void* node_vectors = d_in[2];
    const int* node_specie   = (const int*)d_in[3];
    const int* senders       = (const int*)d_in[4];
    const int* receivers     = (const int*)d_in[5];
    const void* W_up_s       = d_in[6];
    const void* W_up_v       = d_in[7];
    const void* W_skip_s     = d_in[8];
    const void* W_skip_v     = d_in[9];
    const void* W_mlp1       = d_in[10];
    const void* W_mlp2       = d_in[11];
    const void* W_mlp3       = d_in[12];
    const void* W_down_s     = d_in[13];
    const void* W_down_v     = d_in[14];

    char* ws = (char*)d_ws;
    size_t off = 0;
    auto alloc = [&](size_t bytes) { void* p = ws + off; off += (bytes + 255) & ~(size_t)255; return p; };
    unsigned short* hbuf     = (unsigned short*)alloc((size_t)N_NODES * 256 * 2);
    unsigned short* ns_b     = (unsigned short*)alloc((size_t)N_NODES * 64 * 2);
    unsigned short* nv_t     = (unsigned short*)alloc((size_t)N_NODES * 192 * 2);
    unsigned short* agg_s_b  = (unsigned short*)alloc((size_t)N_NODES * 128 * 2);
    unsigned short* agg_v_b  = (unsigned short*)alloc((size_t)N_NODES * 384 * 2);
    unsigned short* mixseg   = (unsigned short*)alloc((size_t)SEG_E * 256 * 2);
    unsigned short* yq       = (unsigned short*)alloc((size_t)N_EDGES * 4 * 2);
    int* cnt        = (int*)alloc((size_t)(N_NODES + 8) * 4);
    int* cnt5       = cnt + N_NODES;
    int* offs       = (int*)alloc((size_t)(N_NODES + 1) * 4);
    int* cursor     = (int*)alloc((size_t)N_NODES * 4);
    int* sorted     = (int*)alloc((size_t)N_EDGES * 4);
    int* sorted_snd = (int*)alloc((size_t)N_EDGES * 4);
    int* sorted_node= (int*)alloc((size_t)N_NODES * 4);
    int* sp_offs    = (int*)alloc(16 * 4);
    int* cursor5    = (int*)alloc(16 * 4);
    int* tile_info  = (int*)alloc(16 * 4);
    int* flag       = (int*)alloc(4);

    detect_kernel<<<dim3(1), dim3(64), 0, stream>>>((const unsigned short*)W_up_s, flag);
    hipMemsetAsync(cnt, 0, (size_t)(N_NODES + 8) * 4, stream);

    hist_kernel<<<dim3(1875), dim3(256), 0, stream>>>(receivers, cnt);
    scan_kernel<<<dim3(1), dim3(1024), 0, stream>>>(cnt, offs, cursor);
    scatter_kernel<<<dim3(1875), dim3(256), 0, stream>>>(receivers, senders, cursor, sorted, sorted_snd);

    hist5_kernel<<<dim3(157), dim3(256), 0, stream>>>(node_specie, cnt5);
    scan5_kernel<<<dim3(1), dim3(64), 0, stream>>>(cnt5, sp_offs, cursor5, tile_info);
    scatter5_kernel<<<dim3(157), dim3(256), 0, stream>>>(node_specie, cursor5, sorted_node);

    node_up_kernel<true><<<dim3(2500), dim3(256), 0, stream>>>(
        node_scalars, node_vectors, W_up_s, W_up_v, hbuf, ns_b, nv_t, flag);
    node_up_kernel<false><<<dim3(2500), dim3(256), 0, stream>>>(
        node_scalars, node_vectors, W_up_s, W_up_v, hbuf, ns_b, nv_t, flag);

    const int MLP_BLOCKS = (SEG_TILES + 7) / 8;   // 938
    for (int s = 0; s < SEG; s++) {
        int p_lo = s * SEG_E;
        mlp_kernel<true><<<dim3(MLP_BLOCKS), dim3(512), 0, stream>>>(
            vectors, sorted, W_mlp1, W_mlp2, W_mlp3, mixseg, yq, p_lo, flag);
        mlp_kernel<false><<<dim3(MLP_BLOCKS), dim3(512), 0, stream>>>(
            vectors, sorted, W_mlp1, W_mlp2, W_mlp3, mixseg, yq, p_lo, flag);
        agg_kernel<<<dim3(10000), dim3(256), 0, stream>>>(
            hbuf, sorted_snd, mixseg, yq, offs, agg_s_b, agg_v_b, p_lo, p_lo + SEG_E);
    }

    node_final_kernel<true><<<dim3(640), dim3(256), 0, stream>>>(
        W_skip_s, W_skip_v, W_down_s, W_down_v, ns_b, nv_t, agg_s_b, agg_v_b,
        sorted_node, sp_offs, tile_info, d_out, flag);
    node_final_kernel<false><<<dim3(640), dim3(256), 0, stream>>>(
        W_skip_s, W_skip_v, W_down_s, W_down_v, ns_b, nv_t, agg_s_b, agg_v_b,
        sorted_node, sp_offs, tile_info, d_out, flag);
}

// Round 7
// 675.812 us; speedup vs baseline: 3.8099x; 1.1348x over previous
//
#include <hip/hip_runtime.h>
#include <hip/hip_bf16.h>

#define N_NODES 40000
#define N_EDGES 480000
#define SEG 4
#define SEG_E (N_EDGES / SEG)      // 120000
#define SEG_TILES (SEG_E / 16)     // 7500
#define SCAN_BLOCKS 157            // ceil(40000/256)

typedef short bf16x8 __attribute__((ext_vector_type(8)));
typedef float f32x4 __attribute__((ext_vector_type(4)));

__device__ __forceinline__ float bf2f(__hip_bfloat16 x) { return __bfloat162float(x); }

__device__ __forceinline__ float lane_bcast(float v, int i) {
    union { float f; int i; } u; u.f = v;
    int r = __builtin_amdgcn_readlane(u.i, i);
    union { int i; float f; } w; w.i = r; return w.f;
}

__device__ __forceinline__ float swishf(float x) { return x / (1.0f + __expf(-x)); }

__device__ __forceinline__ float bflo(unsigned u) { union { unsigned u; float f; } w; w.u = u << 16; return w.f; }
__device__ __forceinline__ float bfhi(unsigned u) { union { unsigned u; float f; } w; w.u = u & 0xffff0000u; return w.f; }
__device__ __forceinline__ float bfu(unsigned short u) { union { unsigned u; float f; } w; w.u = ((unsigned)u) << 16; return w.f; }

__device__ __forceinline__ unsigned short f2bf_bits(float x) {
    union { __hip_bfloat16 h; unsigned short u; } c; c.h = __float2bfloat16(x); return c.u;
}

__constant__ const float INV8 = 0.35355339059327373f;
__constant__ const float INV64 = 0.125f;
__constant__ const float INV128 = 0.08838834764831845f;
__constant__ const float INV_NN = 0.2886751345948129f;   // 1/sqrt(12)
__constant__ const float SQRT2 = 1.4142135623730951f;
__constant__ const float SQRT3 = 1.7320508075688772f;
__constant__ const float INV_SQRT3 = 0.5773502691896258f;
__constant__ const float PI_F = 3.14159265358979323846f;

template<bool F32>
__device__ __forceinline__ float LD(const void* p, int i) {
    if constexpr (F32) return ((const float*)p)[i];
    else return bf2f(((const __hip_bfloat16*)p)[i]);
}
template<bool F32>
__device__ __forceinline__ void ST(void* p, size_t i, float v) {
    if constexpr (F32) ((float*)p)[i] = v;
    else ((__hip_bfloat16*)p)[i] = __float2bfloat16(v);
}

// ---------------- dtype probe ----------------
__global__ void detect_kernel(const unsigned short* __restrict__ w, int* __restrict__ flag) {
    int lane = threadIdx.x;
    int cnt = 0;
    for (int i = lane; i < 2048; i += 64) {
        unsigned e = (w[2 * i] >> 7) & 0xFF;
        if (e >= 110 && e <= 133) cnt++;
    }
    #pragma unroll
    for (int off = 32; off > 0; off >>= 1) cnt += __shfl_down(cnt, off, 64);
    if (lane == 0) *flag = (cnt > 1024) ? 1 : 0;
}

// ---------------- counting sort of edges by receiver ----------------
__global__ __launch_bounds__(256) void hist_kernel(const int* __restrict__ receivers,
                                                   int* __restrict__ cnt) {
    int e = blockIdx.x * 256 + threadIdx.x;
    if (e < N_EDGES) atomicAdd(&cnt[receivers[e]], 1);
}

// Hierarchical scan (replaces the 102-us single-block serial scan):
// stage 1: per-block (256-bin) sums
__global__ __launch_bounds__(256) void partial_kernel(const int* __restrict__ cnt,
                                                      int* __restrict__ partials) {
    __shared__ int red[4];
    int idx = blockIdx.x * 256 + threadIdx.x;
    int v = (idx < N_NODES) ? cnt[idx] : 0;
    #pragma unroll
    for (int off = 32; off > 0; off >>= 1) v += __shfl_down(v, off, 64);
    int wave = threadIdx.x >> 6, lane = threadIdx.x & 63;
    if (lane == 0) red[wave] = v;
    __syncthreads();
    if (threadIdx.x == 0) partials[blockIdx.x] = red[0] + red[1] + red[2] + red[3];
}

// stage 2: scan 157 partials in one block -> exclusive block bases
__global__ __launch_bounds__(256) void scanp_kernel(const int* __restrict__ partials,
                                                    int* __restrict__ pscan) {
    __shared__ int buf[256];
    int t = threadIdx.x;
    int v = (t < SCAN_BLOCKS) ? partials[t] : 0;
    buf[t] = v;
    __syncthreads();
    for (int off = 1; off < 256; off <<= 1) {
        int tmp = (t >= off) ? buf[t - off] : 0;
        __syncthreads();
        buf[t] += tmp;
        __syncthreads();
    }
    if (t < SCAN_BLOCKS) pscan[t] = buf[t] - v;   // exclusive
}

// stage 3: in-block exclusive scan + block base -> offs, cursor
__global__ __launch_bounds__(256) void offs_kernel(const int* __restrict__ cnt,
                                                   const int* __restrict__ pscan,
                                                   int* __restrict__ offs,
                                                   int* __restrict__ cursor) {
    __shared__ int buf[256];
    int b = blockIdx.x, t = threadIdx.x;
    int idx = b * 256 + t;
    int v = (idx < N_NODES) ? cnt[idx] : 0;
    buf[t] = v;
    __syncthreads();
    for (int off = 1; off < 256; off <<= 1) {
        int tmp = (t >= off) ? buf[t - off] : 0;
        __syncthreads();
        buf[t] += tmp;
        __syncthreads();
    }
    int exc = buf[t] - v + pscan[b];
    if (idx < N_NODES) { offs[idx] = exc; cursor[idx] = exc; }
    if (idx == N_NODES - 1) offs[N_NODES] = exc + v;
}

__global__ __launch_bounds__(256) void scatter_kernel(const int* __restrict__ receivers,
                                                      const int* __restrict__ senders,
                                                      int* __restrict__ cursor,
                                                      int* __restrict__ sorted_eid,
                                                      int* __restrict__ sorted_snd) {
    int e = blockIdx.x * 256 + threadIdx.x;
    if (e < N_EDGES) {
        int p = atomicAdd(&cursor[receivers[e]], 1);
        sorted_eid[p] = e;
        sorted_snd[p] = senders[e];
    }
}

// ---------------- counting sort of nodes by species (wave-aggregated atomics) ----------------
__global__ __launch_bounds__(256) void hist5_kernel(const int* __restrict__ specie,
                                                    int* __restrict__ cnt5) {
    int n = blockIdx.x * 256 + threadIdx.x;
    int lane = threadIdx.x & 63;
    int sp = (n < N_NODES) ? specie[n] : -1;
    #pragma unroll
    for (int s = 0; s < 5; s++) {
        unsigned long long mask = __ballot(sp == s);
        if (mask != 0ull) {
            int leader = __builtin_ctzll(mask);
            if (lane == leader) atomicAdd(&cnt5[s], __popcll(mask));
        }
    }
}

// tile_info[0..5] = block_base prefix (blocks of 4 tiles); tile_info[8+s] = tiles of species s
__global__ void scan5_kernel(const int* __restrict__ cnt5, int* __restrict__ sp_offs,
                             int* __restrict__ cursor5, int* __restrict__ tile_info) {
    if (threadIdx.x != 0 || blockIdx.x != 0) return;
    int run = 0, tb = 0;
    for (int s = 0; s < 5; s++) {
        sp_offs[s] = run; cursor5[s] = run;
        tile_info[s] = tb;
        int c = cnt5[s];
        int T = (c + 15) >> 4;
        tile_info[8 + s] = T;
        tb += (T + 3) >> 2;
        run += c;
    }
    sp_offs[5] = run;
    tile_info[5] = tb;
}

__global__ __launch_bounds__(256) void scatter5_kernel(const int* __restrict__ specie,
                                                       int* __restrict__ cursor5,
                                                       int* __restrict__ sorted_node) {
    int n = blockIdx.x * 256 + threadIdx.x;
    int lane = threadIdx.x & 63;
    int sp = (n < N_NODES) ? specie[n] : -1;
    #pragma unroll
    for (int s = 0; s < 5; s++) {
        unsigned long long mask = __ballot(sp == s);
        if (mask != 0ull) {
            int leader = __builtin_ctzll(mask);
            int base = 0;
            if (lane == leader) base = atomicAdd(&cursor5[s], __popcll(mask));
            base = __shfl(base, leader);
            if (sp == s) {
                int prefix = __popcll(mask & ((1ull << lane) - 1ull));
                sorted_node[base + prefix] = n;
            }
        }
    }
}

// ---------------- Kernel A: per-node up-projection (+ bf16 input packing) ----------------
template<bool F32>
__global__ __launch_bounds__(256) void node_up_kernel(
    const void* __restrict__ node_scalars,
    const void* __restrict__ node_vectors,
    const void* __restrict__ W_up_s,
    const void* __restrict__ W_up_v,
    unsigned short* __restrict__ hbuf,
    unsigned short* __restrict__ ns_b,
    unsigned short* __restrict__ nv_t,
    const int* __restrict__ flag)
{
    if ((*flag != 0) == F32) return;
    __shared__ float WsL[4096];
    __shared__ float WvL[4096];
    int tid = threadIdx.x;
    for (int idx = tid; idx < 4096; idx += 256) {
        WsL[idx] = LD<F32>(W_up_s, idx);
        WvL[idx] = LD<F32>(W_up_v, idx);
    }
    __syncthreads();
    int wave = tid >> 6, lane = tid & 63;
    for (int n = blockIdx.x * 4 + wave; n < N_NODES; n += gridDim.x * 4) {
        float s_in = LD<F32>(node_scalars, n * 64 + lane);
        float v0 = LD<F32>(node_vectors, n * 192 + lane * 3 + 0);
        float v1 = LD<F32>(node_vectors, n * 192 + lane * 3 + 1);
        float v2 = LD<F32>(node_vectors, n * 192 + lane * 3 + 2);
        ns_b[(size_t)n * 64 + lane] = f2bf_bits(s_in);
        nv_t[(size_t)n * 64 + lane] = f2bf_bits(v0);
        nv_t[(size_t)N_NODES * 64 + (size_t)n * 64 + lane] = f2bf_bits(v1);
        nv_t[(size_t)N_NODES * 128 + (size_t)n * 64 + lane] = f2bf_bits(v2);
        float hs = 0.f, hv0 = 0.f, hv1 = 0.f, hv2 = 0.f;
        for (int i = 0; i < 64; i++) {
            float si = lane_bcast(s_in, i);
            hs = fmaf(si, WsL[i * 64 + lane], hs);
            float w = WvL[i * 64 + lane];
            hv0 = fmaf(lane_bcast(v0, i), w, hv0);
            hv1 = fmaf(lane_bcast(v1, i), w, hv1);
            hv2 = fmaf(lane_bcast(v2, i), w, hv2);
        }
        uint2 pk;
        pk.x = f2bf_bits(hs * INV64) | ((unsigned)f2bf_bits(hv0 * INV64) << 16);
        pk.y = f2bf_bits(hv1 * INV64) | ((unsigned)f2bf_bits(hv2 * INV64) << 16);
        *(uint2*)(hbuf + (size_t)n * 256 + lane * 4) = pk;
    }
}

// ---------------- Kernel M: MFMA edge MLP (one 16-edge tile per wave) ----------------
template<bool F32>
__global__ __launch_bounds__(512) void mlp_kernel(
    const void* __restrict__ vectors,
    const int* __restrict__ sorted_eid,
    const void* __restrict__ W1,             // [8,64]
    const void* __restrict__ W2,             // [64,64]
    const void* __restrict__ W3,             // [64,256]
    unsigned short* __restrict__ mixseg,     // [SEG_E,256] bf16 bits
    unsigned short* __restrict__ yq,         // [E,4] bf16 bits
    int p_lo,
    const int* __restrict__ flag)
{
    if ((*flag != 0) == F32) return;
    __shared__ unsigned short W3T[256 * 72];
    __shared__ unsigned short W2T[64 * 72];
    __shared__ unsigned short hbl[8 * 64 * 17];
    int tid = threadIdx.x;
    for (int idx = tid; idx < 16384; idx += 512) {
        int o = idx & 255, k = idx >> 8;
        W3T[o * 72 + k] = f2bf_bits(LD<F32>(W3, k * 256 + o));
    }
    for (int idx = tid; idx < 4096; idx += 512) {
        int o = idx & 63, k = idx >> 6;
        W2T[o * 72 + k] = f2bf_bits(LD<F32>(W2, k * 64 + o));
    }
    __syncthreads();
    int wave = tid >> 6, lane = tid & 63;
    int m = lane & 15, q = lane >> 4;
    int tile = blockIdx.x * 8 + wave;
    if (tile >= SEG_TILES) return;
    int p = p_lo + tile * 16 + m;

    int e = sorted_eid[p];
    float vx = LD<F32>(vectors, e * 3 + 0);
    float vy = LD<F32>(vectors, e * 3 + 1);
    float vz = LD<F32>(vectors, e * 3 + 2);
    float len2 = vx * vx + vy * vy + vz * vz;
    float len = sqrtf(len2);
    float Yx = 0.f, Yy = 0.f, Yz = 0.f;
    float rb[8];
    if (len > 0.f) {
        float inv = 1.f / len;
        Yx = SQRT3 * vx * inv; Yy = SQRT3 * vy * inv; Yz = SQRT3 * vz * inv;
        float x6 = len2 * len2 * len2;
        float env = (len < 1.f) ? fmaf(x6, fmaf(len, fmaf(len, -21.f, 48.f), -28.f), 1.f) : 0.f;
        float c = SQRT2 * inv * env;
        #pragma unroll
        for (int k = 0; k < 8; k++) rb[k] = c * __sinf((float)(k + 1) * PI_F * len);
    } else {
        #pragma unroll
        for (int k = 0; k < 8; k++) rb[k] = 0.f;
    }
    if (q == 0) {
        uint2 yw;
        yw.x = f2bf_bits(Yx) | ((unsigned)f2bf_bits(Yy) << 16);
        yw.y = f2bf_bits(Yz);
        *(uint2*)(yq + (size_t)p * 4) = yw;
    }

    f32x4 zero4 = {0.f, 0.f, 0.f, 0.f};
    unsigned short* hb = hbl + wave * (64 * 17);

    bf16x8 b_rb;
    #pragma unroll
    for (int j = 0; j < 8; j++) b_rb[j] = (q == 0) ? (short)f2bf_bits(rb[j]) : (short)0;
    #pragma unroll
    for (int t = 0; t < 4; t++) {
        bf16x8 a;
        #pragma unroll
        for (int j = 0; j < 8; j++) a[j] = 0;
        if (q == 0) {
            #pragma unroll
            for (int j = 0; j < 8; j++)
                a[j] = (short)f2bf_bits(LD<F32>(W1, j * 64 + 16 * t + m));
        }
        f32x4 c = __builtin_amdgcn_mfma_f32_16x16x32_bf16(a, b_rb, zero4, 0, 0, 0);
        #pragma unroll
        for (int r = 0; r < 4; r++)
            hb[(16 * t + 4 * q + r) * 17 + m] = f2bf_bits(swishf(c[r] * INV8));
    }
    bf16x8 b2[2];
    #pragma unroll
    for (int h = 0; h < 2; h++)
        #pragma unroll
        for (int j = 0; j < 8; j++)
            b2[h][j] = (short)hb[(32 * h + 8 * q + j) * 17 + m];
    #pragma unroll
    for (int t = 0; t < 4; t++) {
        bf16x8 a0 = *(const bf16x8*)(W2T + (16 * t + m) * 72 + 8 * q);
        bf16x8 a1 = *(const bf16x8*)(W2T + (16 * t + m) * 72 + 32 + 8 * q);
        f32x4 c = __builtin_amdgcn_mfma_f32_16x16x32_bf16(a0, b2[0], zero4, 0, 0, 0);
        c = __builtin_amdgcn_mfma_f32_16x16x32_bf16(a1, b2[1], c, 0, 0, 0);
        #pragma unroll
        for (int r = 0; r < 4; r++)
            hb[(16 * t + 4 * q + r) * 17 + m] = f2bf_bits(swishf(c[r] * INV64));
    }
    bf16x8 b3[2];
    #pragma unroll
    for (int h = 0; h < 2; h++)
        #pragma unroll
        for (int j = 0; j < 8; j++)
            b3[h][j] = (short)hb[(32 * h + 8 * q + j) * 17 + m];
    size_t rowbase = ((size_t)(tile * 16 + m)) * 256;
    #pragma unroll
    for (int t3 = 0; t3 < 16; t3++) {
        bf16x8 a0 = *(const bf16x8*)(W3T + (16 * t3 + m) * 72 + 8 * q);
        bf16x8 a1 = *(const bf16x8*)(W3T + (16 * t3 + m) * 72 + 32 + 8 * q);
        f32x4 c = __builtin_amdgcn_mfma_f32_16x16x32_bf16(a0, b3[0], zero4, 0, 0, 0);
        c = __builtin_amdgcn_mfma_f32_16x16x32_bf16(a1, b3[1], c, 0, 0, 0);
        uint2 v;
        v.x = f2bf_bits(c[0] * INV64) | ((unsigned)f2bf_bits(c[1] * INV64) << 16);
        v.y = f2bf_bits(c[2] * INV64) | ((unsigned)f2bf_bits(c[3] * INV64) << 16);
        *(uint2*)(mixseg + rowbase + 16 * t3 + 4 * q) = v;
    }
}

// ---------------- Kernel B: lean per-node aggregation (segmented, bf16 out) ----------------
__global__ __launch_bounds__(256) void agg_kernel(
    const unsigned short* __restrict__ hbuf,      // [N,64,4]
    const int* __restrict__ sorted_snd,
    const unsigned short* __restrict__ mixseg,    // [SEG_E,256]
    const unsigned short* __restrict__ yq,        // [E,4]
    const int* __restrict__ offs,
    unsigned short* __restrict__ agg_s_b,         // [N,128] bf16
    unsigned short* __restrict__ agg_v_b,         // [N,384] bf16
    int slo, int shi)
{
    int tid = threadIdx.x, wave = tid >> 6, lane = tid & 63;
    int n = blockIdx.x * 4 + wave;
    if (n >= N_NODES) return;
    int beg = __builtin_amdgcn_readfirstlane(offs[n]);
    int end = __builtin_amdgcn_readfirstlane(offs[n + 1]);
    int lo = beg > slo ? beg : slo;
    int hi = end < shi ? end : shi;
    bool owner = (beg >= slo && beg < shi) || (beg >= shi && shi == N_EDGES);
    if (!owner && hi <= lo) return;
    unsigned short* aS = agg_s_b + (size_t)n * 128;
    unsigned short* aV = agg_v_b + (size_t)n * 384;
    float s0, s1, v0, v1, v2, v3, v4, v5;
    if (owner) {
        s0 = s1 = v0 = v1 = v2 = v3 = v4 = v5 = 0.f;
    } else {
        s0 = bfu(aS[lane]); s1 = bfu(aS[64 + lane]);
        v0 = bfu(aV[lane]); v1 = bfu(aV[64 + lane]); v2 = bfu(aV[128 + lane]);
        v3 = bfu(aV[192 + lane]); v4 = bfu(aV[256 + lane]); v5 = bfu(aV[320 + lane]);
    }
    for (int p = lo; p < hi; p++) {
        int snd = __builtin_amdgcn_readfirstlane(sorted_snd[p]);
        uint2 hbv = *(const uint2*)(hbuf + (size_t)snd * 256 + lane * 4);
        float m_s = bflo(hbv.x), mv0 = bfhi(hbv.x);
        float mv1 = bflo(hbv.y), mv2 = bfhi(hbv.y);
        const unsigned short* mp = mixseg + (size_t)(p - slo) * 256;
        float mix0 = bfu(mp[lane]);
        float mix1 = bfu(mp[64 + lane]);
        float mix2 = bfu(mp[128 + lane]);
        float mix3 = bfu(mp[192 + lane]);
        uint2 yw = *(const uint2*)(yq + (size_t)p * 4);
        float Yx = bflo(yw.x), Yy = bfhi(yw.x), Yz = bflo(yw.y);
        float tp0 = (mv0 * Yx + mv1 * Yy + mv2 * Yz) * INV_SQRT3;
        s0 = fmaf(m_s, mix0, s0);
        s1 = fmaf(tp0, mix1, s1);
        float t1 = m_s * mix3;
        v0 = fmaf(mv0, mix2, v0);
        v1 = fmaf(t1, Yx, v1);
        v2 = fmaf(mv1, mix2, v2);
        v3 = fmaf(t1, Yy, v3);
        v4 = fmaf(mv2, mix2, v4);
        v5 = fmaf(t1, Yz, v5);
    }
    aS[lane] = f2bf_bits(s0); aS[64 + lane] = f2bf_bits(s1);
    aV[lane] = f2bf_bits(v0); aV[64 + lane] = f2bf_bits(v1); aV[128 + lane] = f2bf_bits(v2);
    aV[192 + lane] = f2bf_bits(v3); aV[256 + lane] = f2bf_bits(v4); aV[320 + lane] = f2bf_bits(v5);
}

// ---------------- Kernel C: MFMA down-projection + skip + gate ----------------
template<bool F32>
__global__ __launch_bounds__(256) void node_final_kernel(
    const void* __restrict__ W_skip_s,       // [5,64,128]
    const void* __restrict__ W_skip_v,       // [5,64,64]
    const void* __restrict__ W_down_s,       // [128,128]
    const void* __restrict__ W_down_v,       // [128,64]
    const unsigned short* __restrict__ ns_b,      // [N,64]
    const unsigned short* __restrict__ nv_t,      // [3,N,64]
    const unsigned short* __restrict__ agg_s_b,   // [N,128]
    const unsigned short* __restrict__ agg_v_b,   // [N,384]
    const int* __restrict__ sorted_node,
    const int* __restrict__ sp_offs,         // [6]
    const int* __restrict__ tile_info,       // [16]
    void* __restrict__ out,
    const int* __restrict__ flag)
{
    if ((*flag != 0) == F32) return;
    int b = blockIdx.x;
    if (b >= tile_info[5]) return;
    __shared__ unsigned short As[128 * 200];
    __shared__ unsigned short Av[64 * 200];
    int sp = 0;
    #pragma unroll
    for (int s = 1; s < 5; s++) if (b >= tile_info[s]) sp = s;
    const float SC = INV128 * INV_NN;
    int tid = threadIdx.x;
    for (int idx = tid; idx < 128 * 192; idx += 256) {
        int o = idx / 192, k = idx - o * 192;
        float w = (k < 128) ? LD<F32>(W_down_s, k * 128 + o) * SC
                            : LD<F32>(W_skip_s, sp * 8192 + (k - 128) * 128 + o) * INV64;
        As[o * 200 + k] = f2bf_bits(w);
    }
    for (int idx = tid; idx < 64 * 192; idx += 256) {
        int o = idx / 192, k = idx - o * 192;
        float w = (k < 128) ? LD<F32>(W_down_v, k * 64 + o) * SC
                            : LD<F32>(W_skip_v, sp * 4096 + (k - 128) * 64 + o) * INV64;
        Av[o * 200 + k] = f2bf_bits(w);
    }
    __syncthreads();
    int wave = tid >> 6, lane = tid & 63;
    int m = lane & 15, q = lane >> 4;
    int T = tile_info[8 + sp];
    int tl = (b - tile_info[sp]) * 4 + wave;
    if (tl >= T) return;
    int row = sp_offs[sp] + tl * 16;
    int cnt = sp_offs[sp + 1] - row; if (cnt > 16) cnt = 16;
    int mm = (m < cnt) ? m : 0;
    int node = sorted_node[row + mm];

    bf16x8 bs[6];
    {
        const unsigned short* a = agg_s_b + (size_t)node * 128;
        #pragma unroll
        for (int f = 0; f < 4; f++) bs[f] = *(const bf16x8*)(a + f * 32 + q * 8);
        const unsigned short* s = ns_b + (size_t)node * 64;
        #pragma unroll
        for (int f = 0; f < 2; f++) bs[4 + f] = *(const bf16x8*)(s + f * 32 + q * 8);
    }
    bf16x8 bv[3][6];
    #pragma unroll
    for (int c = 0; c < 3; c++) {
        const unsigned short* a = agg_v_b + (size_t)node * 384 + c * 128;
        #pragma unroll
        for (int f = 0; f < 4; f++) bv[c][f] = *(const bf16x8*)(a + f * 32 + q * 8);
        const unsigned short* s = nv_t + (size_t)c * N_NODES * 64 + (size_t)node * 64;
        #pragma unroll
        for (int f = 0; f < 2; f++) bv[c][4 + f] = *(const bf16x8*)(s + f * 32 + q * 8);
    }
    f32x4 z4 = {0.f, 0.f, 0.f, 0.f};
    float gate[4][4];
    #pragma unroll
    for (int t = 0; t < 4; t++) {
        f32x4 c = z4;
        #pragma unroll
        for (int f = 0; f < 6; f++) {
            bf16x8 a = *(const bf16x8*)(As + (16 * (4 + t) + m) * 200 + f * 32 + q * 8);
            c = __builtin_amdgcn_mfma_f32_16x16x32_bf16(a, bs[f], c, 0, 0, 0);
        }
        #pragma unroll
        for (int r = 0; r < 4; r++) gate[t][r] = swishf(c[r]);
    }
    #pragma unroll
    for (int t = 0; t < 4; t++) {
        f32x4 c = z4;
        #pragma unroll
        for (int f = 0; f < 6; f++) {
            bf16x8 a = *(const bf16x8*)(As + (16 * t + m) * 200 + f * 32 + q * 8);
            c = __builtin_amdgcn_mfma_f32_16x16x32_bf16(a, bs[f], c, 0, 0, 0);
        }
        if (m < cnt) {
            size_t base = (size_t)node * 256 + 16 * t + 4 * q;
            if constexpr (F32) {
                float4 o4 = { swishf(c[0]), swishf(c[1]), swishf(c[2]), swishf(c[3]) };
                *(float4*)((float*)out + base) = o4;
            } else {
                uint2 o2;
                o2.x = f2bf_bits(swishf(c[0])) | ((unsigned)f2bf_bits(swishf(c[1])) << 16);
                o2.y = f2bf_bits(swishf(c[2])) | ((unsigned)f2bf_bits(swishf(c[3])) << 16);
                *(uint2*)((unsigned short*)out + base) = o2;
            }
        }
    }
    #pragma unroll
    for (int t = 0; t < 4; t++) {
        f32x4 c0 = z4, c1 = z4, c2 = z4;
        #pragma unroll
        for (int f = 0; f < 6; f++) {
            bf16x8 a = *(const bf16x8*)(Av + (16 * t + m) * 200 + f * 32 + q * 8);
            c0 = __builtin_amdgcn_mfma_f32_16x16x32_bf16(a, bv[0][f], c0, 0, 0, 0);
            c1 = __builtin_amdgcn_mfma_f32_16x16x32_bf16(a, bv[1][f], c1, 0, 0, 0);
            c2 = __builtin_amdgcn_mfma_f32_16x16x32_bf16(a, bv[2][f], c2, 0, 0, 0);
        }
        if (m < cnt) {
            #pragma unroll
            for (int r = 0; r < 4; r++) {
                float g = gate[t][r];
                int o = 16 * t + 4 * q + r;
                size_t base = (size_t)node * 256 + 64 + (size_t)o * 3;
                ST<F32>(out, base + 0, c0[r] * g);
                ST<F32>(out, base + 1, c1[r] * g);
                ST<F32>(out, base + 2, c2[r] * g);
            }
        }
    }
}

extern "C" void kernel_launch(void* const* d_in, const int* in_sizes, int n_in,
                              void* d_out, int out_size, void* d_ws, size_t ws_size,
                              hipStream_t stream) {
    const void* vectors      = d_in[0];
    const void* node_scalars = d_in[1];
    const void* node_vectors = d_in[2];
    const int* node_specie   = (const int*)d_in[3];
    const int* senders       = (const int*)d_in[4];
    const int* receivers     = (const int*)d_in[5];
    const void* W_up_s       = d_in[6];
    const void* W_up_v       = d_in[7];
    const void* W_skip_s     = d_in[8];
    const void* W_skip_v     = d_in[9];
    const void* W_mlp1       = d_in[10];
    const void* W_mlp2       = d_in[11];
    const void* W_mlp3       = d_in[12];
    const void* W_down_s     = d_in[13];
    const void* W_down_v     = d_in[14];

    char* ws = (char*)d_ws;
    size_t off = 0;
    auto alloc = [&](size_t bytes) { void* p = ws + off; off += (bytes + 255) & ~(size_t)255; return p; };
    unsigned short* hbuf     = (unsigned short*)alloc((size_t)N_NODES * 256 * 2);
    unsigned short* ns_b     = (unsigned short*)alloc((size_t)N_NODES * 64 * 2);
    unsigned short* nv_t     = (unsigned short*)alloc((size_t)N_NODES * 192 * 2);
    unsigned short* agg_s_b  = (unsigned short*)alloc((size_t)N_NODES * 128 * 2);
    unsigned short* agg_v_b  = (unsigned short*)alloc((size_t)N_NODES * 384 * 2);
    unsigned short* mixseg   = (unsigned short*)alloc((size_t)SEG_E * 256 * 2);
    unsigned short* yq       = (unsigned short*)alloc((size_t)N_EDGES * 4 * 2);
    int* cnt        = (int*)alloc((size_t)(N_NODES + 8) * 4);
    int* cnt5       = cnt + N_NODES;
    int* offs       = (int*)alloc((size_t)(N_NODES + 1) * 4);
    int* cursor     = (int*)alloc((size_t)N_NODES * 4);
    int* sorted     = (int*)alloc((size_t)N_EDGES * 4);
    int* sorted_snd = (int*)alloc((size_t)N_EDGES * 4);
    int* sorted_node= (int*)alloc((size_t)N_NODES * 4);
    int* sp_offs    = (int*)alloc(16 * 4);
    int* cursor5    = (int*)alloc(16 * 4);
    int* tile_info  = (int*)alloc(16 * 4);
    int* partials   = (int*)alloc((size_t)(SCAN_BLOCKS + 1) * 4);
    int* pscan      = (int*)alloc((size_t)(SCAN_BLOCKS + 1) * 4);
    int* flag       = (int*)alloc(4);

    detect_kernel<<<dim3(1), dim3(64), 0, stream>>>((const unsigned short*)W_up_s, flag);
    hipMemsetAsync(cnt, 0, (size_t)(N_NODES + 8) * 4, stream);

    hist_kernel<<<dim3(1875), dim3(256), 0, stream>>>(receivers, cnt);
    partial_kernel<<<dim3(SCAN_BLOCKS), dim3(256), 0, stream>>>(cnt, partials);
    scanp_kernel<<<dim3(1), dim3(256), 0, stream>>>(partials, pscan);
    offs_kernel<<<dim3(SCAN_BLOCKS), dim3(256), 0, stream>>>(cnt, pscan, offs, cursor);
    scatter_kernel<<<dim3(1875), dim3(256), 0, stream>>>(receivers, senders, cursor, sorted, sorted_snd);

    hist5_kernel<<<dim3(157), dim3(256), 0, stream>>>(node_specie, cnt5);
    scan5_kernel<<<dim3(1), dim3(64), 0, stream>>>(cnt5, sp_offs, cursor5, tile_info);
    scatter5_kernel<<<dim3(157), dim3(256), 0, stream>>>(node_specie, cursor5, sorted_node);

    node_up_kernel<true><<<dim3(2500), dim3(256), 0, stream>>>(
        node_scalars, node_vectors, W_up_s, W_up_v, hbuf, ns_b, nv_t, flag);
    node_up_kernel<false><<<dim3(2500), dim3(256), 0, stream>>>(
        node_scalars, node_vectors, W_up_s, W_up_v, hbuf, ns_b, nv_t, flag);

    const int MLP_BLOCKS = (SEG_TILES + 7) / 8;   // 938
    for (int s = 0; s < SEG; s++) {
        int p_lo = s * SEG_E;
        mlp_kernel<true><<<dim3(MLP_BLOCKS), dim3(512), 0, stream>>>(
            vectors, sorted, W_mlp1, W_mlp2, W_mlp3, mixseg, yq, p_lo, flag);
        mlp_kernel<false><<<dim3(MLP_BLOCKS), dim3(512), 0, stream>>>(
            vectors, sorted, W_mlp1, W_mlp2, W_mlp3, mixseg, yq, p_lo, flag);
        agg_kernel<<<dim3(10000), dim3(256), 0, stream>>>(
            hbuf, sorted_snd, mixseg, yq, offs, agg_s_b, agg_v_b, p_lo, p_lo + SEG_E);
    }

    node_final_kernel<true><<<dim3(640), dim3(256), 0, stream>>>(
        W_skip_s, W_skip_v, W_down_s, W_down_v, ns_b, nv_t, agg_s_b, agg_v_b,
        sorted_node, sp_offs, tile_info, d_out, flag);
    node_final_kernel<false><<<dim3(640), dim3(256), 0, stream>>>(
        W_skip_s, W_skip_v, W_down_s, W_down_v, ns_b, nv_t, agg_s_b, agg_v_b,
        sorted_node, sp_offs, tile_info, d_out, flag);
}